// Round 8
// baseline (191.181 us; speedup 1.0000x reference)
//
#include <hip/hip_runtime.h>

// Problem constants (fixed by setup_inputs / reference)
#define BN  4       // batch
#define NPT 16384   // points per batch
#define NCC 1024    // FPS centroids (cap on unique orbit length)
#define KNN 32      // neighbors

// KNN select parameters
#define HBINS    2048   // 11-bit level-1 histogram
#define CCH      2      // centroids per chunk-block (keys fit in regs)
#define CAND_CAP 768    // boundary-bin candidate cap (overflow -> exact drill)

#define NBLK 64         // fused-kernel grid (all co-resident on 256 CUs)

// Workspace layout (bytes). ~310 KB + flag counters.
#define OFF_CCOUNT 0                          // BN ints
#define OFF_SCOUNT 64                         // BN ints
#define OFF_SBITS  128                        // BN*(NPT/32) u32 = 8 KB
#define OFF_POOL   (128 + BN*(NPT/32)*4)      // BN*NCC floats = 16 KB
#define OFF_CLIST  (OFF_POOL + BN*NCC*4)      // BN*NCC ints = 16 KB
#define OFF_H1     (OFF_CLIST + BN*NCC*4)     // BN*512 floats = 8 KB
#define OFF_H2     (OFF_H1 + BN*512*4)        // BN*256 floats = 4 KB
#define OFF_SLIST  (OFF_H2 + BN*256*4)        // BN*NPT ints = 256 KB
#define OFF_BAR    (OFF_SLIST + BN*NPT*4)     // 20 counters x 64B = 1280 B

typedef short bf16x8 __attribute__((ext_vector_type(8)));
typedef float f32x4  __attribute__((ext_vector_type(4)));
typedef float f32x2  __attribute__((ext_vector_type(2)));

__device__ __forceinline__ short f2bf(float f) {   // RNE fp32 -> bf16
    unsigned u = __float_as_uint(f);
    return (short)((u + 0x7fffu + ((u >> 16) & 1u)) >> 16);
}
__device__ __forceinline__ bf16x8 cvt8(const float* __restrict__ p) {
    bf16x8 v;
#pragma unroll
    for (int j = 0; j < 8; ++j) v[j] = f2bf(p[j]);
    return v;
}

// ---------------------------------------------------------------------------
// Cross-block transport: every word that crosses a block boundary moves as a
// RELAXED AGENT-scope atomic (sc1 -> coherence point). No fences needed.
// ---------------------------------------------------------------------------
template <typename T>
__device__ __forceinline__ void ast(T* p, T v) {
    __hip_atomic_store(p, v, __ATOMIC_RELAXED, __HIP_MEMORY_SCOPE_AGENT);
}
template <typename T>
__device__ __forceinline__ T ald(const T* p) {
    return __hip_atomic_load(const_cast<T*>(p), __ATOMIC_RELAXED, __HIP_MEMORY_SCOPE_AGENT);
}

// ---------------------------------------------------------------------------
// Producer-consumer sync (replaces 64-arrival grid barriers; R8 hypothesis:
// the 64 same-line fetch_add arrival convoy was ~3-6us of each barrier's
// ~7-8us cost). Few writers per flag (<=16); consumers poll READ-ONLY with
// backoff (damps the R7 poll-storm). signal's __syncthreads drains each
// wave's vmcnt before s_barrier => all sc1 data committed before the flag.
// Counters live 64B apart: flag(phase,b) = bar[(phase*4+b)*16].
// ---------------------------------------------------------------------------
__device__ __forceinline__ void signal_flag(unsigned* __restrict__ c) {
    __syncthreads();
    if (threadIdx.x == 0)
        __hip_atomic_fetch_add(c, 1u, __ATOMIC_RELAXED, __HIP_MEMORY_SCOPE_AGENT);
}
__device__ __forceinline__ void wait_flag(unsigned* __restrict__ c, unsigned n) {
    if (threadIdx.x == 0) {
        int spins = 0;
        while (__hip_atomic_load(c, __ATOMIC_RELAXED, __HIP_MEMORY_SCOPE_AGENT) < n) {
            if (spins < 8) { __builtin_amdgcn_s_sleep(2); ++spins; }
            else            __builtin_amdgcn_s_sleep(16);
        }
    }
    __syncthreads();
}

__device__ __forceinline__ unsigned key_of(float px, float py, float pz, float xn,
                                           float cx, float cy, float cz, float cn)
{
    float dot = __fadd_rn(__fadd_rn(__fmul_rn(cx,px), __fmul_rn(cy,py)), __fmul_rn(cz,pz));
    float d2  = __fsub_rn(__fadd_rn(cn, xn), __fmul_rn(2.0f, dot));
    unsigned u = __float_as_uint(d2);
    return u ^ ((u >> 31) ? 0xFFFFFFFFu : 0x80000000u);
}

__device__ __forceinline__ void wave_scan_bins(const unsigned* __restrict__ H,
    int nbins, int rem, int lane, int* __restrict__ out_bin, int* __restrict__ out_below)
{
    int per = nbins >> 6;
    int base = lane * per;
    unsigned part = 0;
    for (int q = 0; q < per; ++q) part += H[base + q];
    unsigned inc = part;
#pragma unroll
    for (int m = 1; m < 64; m <<= 1) {
        unsigned u = __shfl_up(inc, m, 64);
        if (lane >= m) inc += u;
    }
    unsigned exc = inc - part;
    unsigned long long mk = __ballot(exc < (unsigned)rem && inc >= (unsigned)rem);
    int src = __ffsll((long long)mk) - 1;
    if (lane == src) {
        unsigned run = exc; int bb = base;
        for (int q = 0; q < per; ++q) {
            unsigned h = H[base + q];
            if (run + h >= (unsigned)rem) { bb = base + q; break; }
            run += h;
        }
        *out_bin = bb; *out_below = (int)run;
    }
}

#define MFMA16(a, bfr, c) __builtin_amdgcn_mfma_f32_16x16x32_bf16(a, bfr, c, 0, 0, 0)

// ---------------------------------------------------------------------------
// Fused pipeline, R5 topology (block->work mapping byte-identical to the
// proven 72us kernel): FPS(v7) -> KNN(v5) -> MLP(v4) -> head1 -> head2 ->
// head3. Sync = producer-consumer flags (above) instead of grid barriers.
// ---------------------------------------------------------------------------
__global__ __launch_bounds__(1024) void mega_kernel(const float* __restrict__ x,
    const int* __restrict__ far_init,
    const float* __restrict__ w1, const float* __restrict__ b1,
    const float* __restrict__ w2, const float* __restrict__ b2,
    const float* __restrict__ w3, const float* __restrict__ b3,
    const float* __restrict__ w4, const float* __restrict__ b4,
    const float* __restrict__ w5, const float* __restrict__ b5,
    const float* __restrict__ fw1, const float* __restrict__ fb1,
    const float* __restrict__ fw2, const float* __restrict__ fb2,
    const float* __restrict__ fw3, const float* __restrict__ fb3,
    int* __restrict__ clist, int* __restrict__ ccount, int* __restrict__ scount,
    unsigned* __restrict__ sbits, int* __restrict__ slist, float* __restrict__ pool,
    float* __restrict__ h1g, float* __restrict__ h2g, float* __restrict__ out,
    unsigned* __restrict__ bar)
{
    const int blk = blockIdx.x, t = threadIdx.x;
    const int bb = blk & 3;            // this block's batch for all phases
    // flag arrays: F=fps, K=knn, M=mlp, H1, H2 -- 64B-spaced counters
    unsigned* F  = bar + (0*4 + bb) * 16;
    unsigned* K  = bar + (1*4 + bb) * 16;
    unsigned* M  = bar + (2*4 + bb) * 16;
    unsigned* H1 = bar + (3*4 + bb) * 16;
    unsigned* H2 = bar + (4*4 + bb) * 16;
    // LDS overlay: max(FPS 16.6K, KNN 22.6K, MLP 36.6K, heads 4K)
    __shared__ __align__(16) char smem[36864];

    // ============ Phase 0: FPS (v7, absmax-0.0-verified R1/R5) ==============
    {
#pragma clang fp contract(off)
        if (blk < 4) {
            const int b = blk;
            unsigned char* seen   = (unsigned char*)smem;
            unsigned*      vslot  = (unsigned*)(smem + 16384);
            int*           islot  = (int*)(smem + 16384 + 8);
            int*           nmatch = (int*)(smem + 16384 + 16);
            int4*          cslot  = (int4*)(smem + 16384 + 32);  // [2][4]

            // ---- workspace zeroing for this batch (sc1: visible to all) ----
            if (t < 512) ast(&sbits[b*(NPT/32) + t], 0u);  // 512 u32
            ast(&pool[b*NCC + t], 0.0f);                   // 1024 floats
            if (t == 0) { ast(&ccount[b], 0); ast(&scount[b], 0); }

            const float* xb = x + (size_t)b * NPT * 3;
            f32x2 px[8], py[8], pz[8];
#pragma unroll
            for (int r = 0; r < 8; ++r) {
                int ia = t + ((2*r) << 10), ib = ia + 1024;
                px[r] = f32x2{xb[ia*3+0], xb[ib*3+0]};
                py[r] = f32x2{xb[ia*3+1], xb[ib*3+1]};
                pz[r] = f32x2{xb[ia*3+2], xb[ib*3+2]};
            }
            ((uint4*)seen)[t] = make_uint4(0,0,0,0);      // 1024 * 16B = 16 KB
            if (t == 0) {
                vslot[0] = 0u;         vslot[1] = 0u;
                islot[0] = 0x7fffffff; islot[1] = 0x7fffffff;
                nmatch[0] = 0;         nmatch[1] = 0;
            }
            int prev_bx = far_init[b];                    // uniform
            __syncthreads();
            int pbs = __builtin_amdgcn_readfirstlane(prev_bx);
            float cx = xb[pbs*3], cy = xb[pbs*3+1], cz = xb[pbs*3+2];

            int done = 0;
            for (int it = 0; it < NCC-1; ++it) {
                const int p = it & 1;
                const f32x2 cX = {cx, cx}, cY = {cy, cy}, cZ = {cz, cz};
                f32x2 sv[8];
                f32x2 rm = {0.0f, 0.0f};                  // distances >= 0
#pragma unroll
                for (int r = 0; r < 8; ++r) {
                    f32x2 dx = px[r] - cX;
                    f32x2 dy = py[r] - cY;
                    f32x2 dz = pz[r] - cZ;
                    f32x2 m1 = dx * dx;
                    f32x2 m2 = dy * dy;
                    f32x2 m3 = dz * dz;
                    f32x2 s  = (m1 + m2) + m3;            // exact grouping of reference
                    sv[r] = s;
                    rm.x = fmaxf(rm.x, s.x);
                    rm.y = fmaxf(rm.y, s.y);
                }
                float tm = fmaxf(rm.x, rm.y);
#pragma unroll
                for (int m = 1; m < 64; m <<= 1)
                    tm = fmaxf(tm, __shfl_xor(tm, m, 64)); // wave-uniform max
                if ((t & 63) == 0) atomicMax(&vslot[p], __float_as_uint(tm));
                if (t == 0) seen[prev_bx] = 1;            // pre-barrier write
                __syncthreads();                          // B1: block max final
                const unsigned bmax = vslot[p];
                if (t == 0) {                             // prep other parity
                    vslot[p^1] = 0u; islot[p^1] = 0x7fffffff; nmatch[p^1] = 0;
                }
                if (__float_as_uint(tm) == bmax) {        // wave-uniform: ~1/16 waves
                    int   myidx = 0x7fffffff;
                    float mx = 0.f, my = 0.f, mz = 0.f;
#pragma unroll
                    for (int r = 0; r < 8; ++r) {
                        int ia = t + ((2*r) << 10);
                        if (__float_as_uint(sv[r].x) == bmax && ia < myidx)
                            { myidx = ia;        mx = px[r].x; my = py[r].x; mz = pz[r].x; }
                        if (__float_as_uint(sv[r].y) == bmax && ia + 1024 < myidx)
                            { myidx = ia + 1024; mx = px[r].y; my = py[r].y; mz = pz[r].y; }
                    }
                    if (myidx != 0x7fffffff) {
                        atomicMin(&islot[p], myidx);      // first-index tie-break
                        int cs = atomicAdd(&nmatch[p], 1);
                        if (cs < 4)
                            cslot[p*4 + cs] = make_int4(myidx, __float_as_int(mx),
                                                        __float_as_int(my), __float_as_int(mz));
                    }
                }
                __syncthreads();                          // B2: winner final
                const int bx = islot[p];
                if (seen[bx]) { done = 1; break; }        // uniform
                prev_bx = bx;
                const int nm = nmatch[p] < 4 ? nmatch[p] : 4;
                bool got = false;
                float nx = 0.f, ny = 0.f, nz = 0.f;
#pragma unroll
                for (int csi = 0; csi < 4; ++csi) {       // LDS broadcast
                    if (csi < nm) {
                        int4 v = cslot[p*4 + csi];
                        if (v.x == bx) {
                            nx = __int_as_float(v.y); ny = __int_as_float(v.z);
                            nz = __int_as_float(v.w); got = true;
                        }
                    }
                }
                if (got) { cx = nx; cy = ny; cz = nz; }   // no L2 round-trip
                else {                                    // tie/overflow fallback
                    int bxs = __builtin_amdgcn_readfirstlane(bx);
                    cx = xb[bxs*3]; cy = xb[bxs*3+1]; cz = xb[bxs*3+2];
                }
            }
            if (!done && t == 0) seen[prev_bx] = 1;       // full orbit: mark last
            __syncthreads();
#pragma unroll
            for (int j = 0; j < 16; ++j) {
                int idx = t + (j << 10);
                if (seen[idx]) {
                    int pos = atomicAdd(&ccount[b], 1);
                    ast(&clist[b * NCC + pos], idx);
                }
            }
            signal_flag(F);                               // F[b] = 1
        }
    }
    wait_flag(F, 1);                                      // KNN needs only batch bb

    // ======================= Phase 1: KNN (v5, proven) ======================
    // R5 mapping: block handles chunks {blk>>2, blk>>2+16, ...} of batch blk&3.
    {
        const int b = bb;
        const int cnt = ald(&ccount[b]);
        unsigned* hist    = (unsigned*)smem;               // 16384 B
        unsigned* cand    = (unsigned*)(smem + 16384);     // 6144 B
        float*    cpx     = (float*)(smem + 22528);
        float*    cpy     = cpx + CCH;
        float*    cpz     = cpy + CCH;
        float*    cpn     = cpz + CCH;
        unsigned* candCnt = (unsigned*)(cpn + CCH);
        int*      s_bb    = (int*)(candCnt + CCH);
        int*      s_below = s_bb + CCH;
        int*      s_rrem  = s_below + CCH;
        int*      s_need  = s_rrem + CCH;
        int*      s_pref  = s_need + CCH;
        unsigned* s_tau   = (unsigned*)(s_pref + CCH);
        int*      s_tb    = (int*)(s_tau + CCH);           // [0]=tbin [1]=tbelow

        const int lane = t & 63, w = t >> 6;
        const float* xb = x + (size_t)b * NPT * 3;

        for (int ch = blk >> 2; ch * CCH < cnt; ch += 16) {
            const int cbase = ch * CCH;

            __syncthreads();                               // defensive item fence
            if (t < CCH) {
                int ci = ald(&clist[b * NCC + min(cbase + t, cnt - 1)]);  // tail-clamp dup
                float cx = xb[ci*3], cy = xb[ci*3+1], cz = xb[ci*3+2];
                cpx[t] = cx; cpy[t] = cy; cpz[t] = cz;
                cpn[t] = __fadd_rn(__fadd_rn(__fmul_rn(cx,cx), __fmul_rn(cy,cy)), __fmul_rn(cz,cz));
                candCnt[t] = 0;
            }
            for (int i = t; i < CCH * HBINS; i += 1024) hist[i] = 0;
            __syncthreads();

            // Sweep 1: compute keys ONCE into registers + build histograms.
            unsigned keys[NPT/1024][CCH];                  // 16 x 2 u32 = 32 VGPRs
#pragma unroll
            for (int j = 0; j < NPT/1024; ++j) {
                int i = t + (j << 10);
                float px = xb[i*3], py = xb[i*3+1], pz = xb[i*3+2];
                float xn = __fadd_rn(__fadd_rn(__fmul_rn(px,px), __fmul_rn(py,py)), __fmul_rn(pz,pz));
#pragma unroll
                for (int c = 0; c < CCH; ++c) {
                    unsigned key = key_of(px,py,pz,xn, cpx[c],cpy[c],cpz[c],cpn[c]);
                    keys[j][c] = key;
                    atomicAdd(&hist[c*HBINS + (key >> 21)], 1u);
                }
            }
            __syncthreads();

            if (w < CCH)
                wave_scan_bins(&hist[w*HBINS], HBINS, KNN, lane, &s_bb[w], &s_below[w]);
            __syncthreads();
            if (t < CCH) s_rrem[t] = KNN - s_below[t];
            __syncthreads();

            // Sweep 2 (registers only): collect candidate keys in boundary bins.
#pragma unroll
            for (int j = 0; j < NPT/1024; ++j) {
#pragma unroll
                for (int c = 0; c < CCH; ++c) {
                    unsigned key = keys[j][c];
                    if ((int)(key >> 21) == s_bb[c]) {
                        unsigned pos = atomicAdd(&candCnt[c], 1u);
                        if (pos < CAND_CAP) cand[c*CAND_CAP + pos] = key;
                    }
                }
            }
            __syncthreads();

            // Exact tau: rank-select per wave.
            if (w < CCH) {
                unsigned cc = candCnt[w];
                if (cc <= CAND_CAP) {
                    int r = s_rrem[w] - 1;
                    const unsigned* C = &cand[w*CAND_CAP];
                    for (int idx = lane; idx < (int)cc; idx += 64) {
                        unsigned k = C[idx]; int rank = 0;
                        for (int q = 0; q < (int)cc; ++q) {
                            unsigned kq = C[q];
                            rank += (kq < k || (kq == k && q < idx)) ? 1 : 0;
                        }
                        if (rank == r) s_tau[w] = k;
                    }
                    if (lane == 0) s_need[w] = 0;
                } else if (lane == 0) s_need[w] = 1;
            }
            __syncthreads();

            // Rare exact drill-down for overflowed boundary bins.
            for (int c = 0; c < CCH; ++c) {
                if (s_need[c]) {
                    const float cx = cpx[c], cy = cpy[c], cz = cpz[c], cn = cpn[c];
                    for (int i = t; i < HBINS; i += 1024) hist[i] = 0;
                    __syncthreads();
                    for (int j = 0; j < NPT/1024; ++j) {
                        int i = t + (j << 10);
                        float px = xb[i*3], py = xb[i*3+1], pz = xb[i*3+2];
                        float xn = __fadd_rn(__fadd_rn(__fmul_rn(px,px), __fmul_rn(py,py)), __fmul_rn(pz,pz));
                        unsigned key = key_of(px,py,pz,xn, cx,cy,cz,cn);
                        if ((int)(key >> 21) == s_bb[c]) atomicAdd(&hist[(key >> 10) & 2047u], 1u);
                    }
                    __syncthreads();
                    if (w == 0) wave_scan_bins(hist, HBINS, s_rrem[c], lane, &s_tb[0], &s_tb[1]);
                    __syncthreads();
                    if (t == 0) { s_pref[c] = (s_bb[c] << 11) | s_tb[0]; s_rrem[c] -= s_tb[1]; }
                    __syncthreads();
                    for (int i = t; i < 1024; i += 1024) hist[i] = 0;
                    __syncthreads();
                    for (int j = 0; j < NPT/1024; ++j) {
                        int i = t + (j << 10);
                        float px = xb[i*3], py = xb[i*3+1], pz = xb[i*3+2];
                        float xn = __fadd_rn(__fadd_rn(__fmul_rn(px,px), __fmul_rn(py,py)), __fmul_rn(pz,pz));
                        unsigned key = key_of(px,py,pz,xn, cx,cy,cz,cn);
                        if ((int)(key >> 10) == s_pref[c]) atomicAdd(&hist[key & 1023u], 1u);
                    }
                    __syncthreads();
                    if (w == 0) wave_scan_bins(hist, 1024, s_rrem[c], lane, &s_tb[0], &s_tb[1]);
                    __syncthreads();
                    if (t == 0) s_tau[c] = (((unsigned)s_pref[c]) << 10) | (unsigned)s_tb[0];
                    __syncthreads();
                }
            }
            __syncthreads();

            // Sweep 3 (registers only): union-mark + build compacted list (deduped).
#pragma unroll
            for (int j = 0; j < NPT/1024; ++j) {
                int i = t + (j << 10);
                bool sel = false;
#pragma unroll
                for (int c = 0; c < CCH; ++c) sel |= (keys[j][c] <= s_tau[c]);
                if (sel) {
                    unsigned bit = 1u << (i & 31);
                    unsigned old = atomicOr(&sbits[b*(NPT/32) + (i >> 5)], bit);
                    if (!(old & bit)) {
                        int pos = atomicAdd(&scount[b], 1);
                        ast(&slist[b * NPT + pos], i);
                    }
                }
            }
        }
    }
    signal_flag(K);                                        // 16 writers per batch
    wait_flag(K, 16);

    // ======================= Phase 2: MLP (v4, proven) ======================
    {
        const int b = bb;
        const int cnt = ald(&scount[b]);
        short* A1 = (short*)smem;                 // 64*72*2 = 9216
        short* A2 = (short*)(smem + 9216);        // 9216
        short* A3 = (short*)(smem + 18432);       // 64*136*2 = 17408
        float* sx = (float*)(smem + 35840);       // 3*64*4 = 768

        const int lane = t & 63;
        const int w    = __builtin_amdgcn_readfirstlane(t >> 6);  // 0..15
        const int m    = lane & 15, quad = lane >> 4;
        const int z    = (blk >> 2) & 3;          // block-constant oc5 slice

        // hoisted weight fragments (block-constant)
        const int ocA = (w >> 2) * 16 + m;
        bf16x8 bw2[2], bw3[2], bw4[2][2], bw5[4];
#pragma unroll
        for (int ks = 0; ks < 2; ++ks) {
            bw2[ks] = cvt8(w2 + ocA*64 + ks*32 + quad*8);
            bw3[ks] = cvt8(w3 + ocA*64 + ks*32 + quad*8);
        }
        int oc4i[2];
#pragma unroll
        for (int r2 = 0; r2 < 2; ++r2) {
            oc4i[r2] = ((w >> 2) + 4*r2) * 16 + m;
#pragma unroll
            for (int ks = 0; ks < 2; ++ks)
                bw4[r2][ks] = cvt8(w4 + oc4i[r2]*64 + ks*32 + quad*8);
        }
        const int oc5 = z*256 + w*16 + m;
#pragma unroll
        for (int ks = 0; ks < 4; ++ks)
            bw5[ks] = cvt8(w5 + oc5*128 + ks*32 + quad*8);
        const float bias2 = b2[ocA], bias3 = b3[ocA];
        const float bias4_0 = b4[oc4i[0]], bias4_1 = b4[oc4i[1]];
        const float bias5 = b5[oc5];
        float w1v[4][3], b1v[4];
#pragma unroll
        for (int i = 0; i < 4; ++i) {
            int oc = w*4 + i;
            w1v[i][0] = w1[oc*3+0]; w1v[i][1] = w1[oc*3+1]; w1v[i][2] = w1[oc*3+2];
            b1v[i] = b1[oc];
        }
        const int pt0 = (w & 3) * 16;             // pt tile for L2/L3/L4

        for (int xblk = blk >> 4; xblk * 64 < cnt; xblk += 4) {
            const int base = xblk << 6;
            const int npts = min(64, cnt - base);
            __syncthreads();                       // prev tile fully consumed
            if (t < 64) {
                int idx = ald(&slist[b * NPT + base + min(t, npts - 1)]);  // pad = dup last
                const float* xp = x + ((size_t)b * NPT + idx) * 3;
                sx[t] = xp[0]; sx[64 + t] = xp[1]; sx[128 + t] = xp[2];
            }
            __syncthreads();
            {   // L1: 3->64, fp32 VALU, write bf16 [pt][72]
                float x0 = sx[lane], x1 = sx[64 + lane], x2 = sx[128 + lane];
#pragma unroll
                for (int i = 0; i < 4; ++i) {
                    float acc = fmaf(x2, w1v[i][2], fmaf(x1, w1v[i][1],
                                 fmaf(x0, w1v[i][0], b1v[i])));
                    A1[lane*72 + w*4 + i] = f2bf(fmaxf(acc, 0.0f));
                }
            }
            __syncthreads();
            {   // L2: A1 -> A2 (64->64)
                bf16x8 a0 = *(const bf16x8*)&A1[(pt0 + m)*72 + quad*8];
                bf16x8 a1 = *(const bf16x8*)&A1[(pt0 + m)*72 + 32 + quad*8];
                f32x4 d = {0.f, 0.f, 0.f, 0.f};
                d = MFMA16(a0, bw2[0], d);
                d = MFMA16(a1, bw2[1], d);
#pragma unroll
                for (int r = 0; r < 4; ++r)
                    A2[(pt0 + quad*4 + r)*72 + ocA] = f2bf(fmaxf(d[r] + bias2, 0.0f));
            }
            __syncthreads();
            {   // L3: A2 -> A1 (64->64)
                bf16x8 a0 = *(const bf16x8*)&A2[(pt0 + m)*72 + quad*8];
                bf16x8 a1 = *(const bf16x8*)&A2[(pt0 + m)*72 + 32 + quad*8];
                f32x4 d = {0.f, 0.f, 0.f, 0.f};
                d = MFMA16(a0, bw3[0], d);
                d = MFMA16(a1, bw3[1], d);
#pragma unroll
                for (int r = 0; r < 4; ++r)
                    A1[(pt0 + quad*4 + r)*72 + ocA] = f2bf(fmaxf(d[r] + bias3, 0.0f));
            }
            __syncthreads();
            {   // L4: A1 -> A3 (64->128), 2 oc-tiles per wave
                bf16x8 a0 = *(const bf16x8*)&A1[(pt0 + m)*72 + quad*8];
                bf16x8 a1 = *(const bf16x8*)&A1[(pt0 + m)*72 + 32 + quad*8];
#pragma unroll
                for (int r2 = 0; r2 < 2; ++r2) {
                    f32x4 d = {0.f, 0.f, 0.f, 0.f};
                    d = MFMA16(a0, bw4[r2][0], d);
                    d = MFMA16(a1, bw4[r2][1], d);
                    float bs = r2 ? bias4_1 : bias4_0;
#pragma unroll
                    for (int r = 0; r < 4; ++r)
                        A3[(pt0 + quad*4 + r)*136 + oc4i[r2]] = f2bf(fmaxf(d[r] + bs, 0.0f));
                }
            }
            __syncthreads();
            {   // L5 (128 -> this block's 256-oc slice) + max-pool
                float vm = 0.0f;                   // relu outputs >= 0
#pragma unroll
                for (int pt4 = 0; pt4 < 4; ++pt4) {
                    const int q0 = pt4 * 16;
                    f32x4 d = {0.f, 0.f, 0.f, 0.f};
#pragma unroll
                    for (int ks = 0; ks < 4; ++ks) {
                        bf16x8 a = *(const bf16x8*)&A3[(q0 + m)*136 + ks*32 + quad*8];
                        d = MFMA16(a, bw5[ks], d);
                    }
#pragma unroll
                    for (int r = 0; r < 4; ++r)
                        vm = fmaxf(vm, fmaxf(d[r] + bias5, 0.0f));
                }
                vm = fmaxf(vm, __shfl_xor(vm, 16, 64));
                vm = fmaxf(vm, __shfl_xor(vm, 32, 64));
                if (lane < 16)
                    atomicMax((int*)&pool[b*NCC + z*256 + w*16 + lane], __float_as_int(vm));
            }
        }
    }
    signal_flag(M);                                        // 16 writers per batch
    wait_flag(M, 16);

    // ======================= Phase 3: head1 (proven) ========================
    {
        const int bo = blk >> 2, b = bb;           // 16 blocks x 32 rows = 512
        const int lane = t & 63, w = t >> 6;
        float* g = (float*)smem;                   // 4 KB
        g[t] = ald(&pool[b*NCC + t]);
        __syncthreads();
#pragma unroll
        for (int i = 0; i < 2; ++i) {
            int o = bo * 32 + w * 2 + i;
            float acc = 0.0f;
#pragma unroll
            for (int j = 0; j < 16; ++j) {
                int k = lane + (j << 6);
                acc += g[k] * fw1[o*1024 + k];
            }
#pragma unroll
            for (int m = 1; m < 64; m <<= 1) acc += __shfl_xor(acc, m, 64);
            if (lane == 0) ast(&h1g[b*512 + o], fmaxf(acc + fb1[o], 0.0f));
        }
    }
    signal_flag(H1);                                       // 16 writers per batch
    if (blk >= 32) return;                                 // done with all roles
    wait_flag(H1, 16);

    // ======================= Phase 4: head2 (proven) ========================
    {
        const int bo = blk >> 2, b = bb;           // 8 blocks x 32 rows = 256
        const int lane = t & 63, w = t >> 6;
        float* h1 = (float*)smem;                  // 2 KB
        if (t < 512) h1[t] = ald(&h1g[b*512 + t]);
        __syncthreads();
#pragma unroll
        for (int i = 0; i < 2; ++i) {
            int o = bo * 32 + w * 2 + i;
            float acc = 0.0f;
#pragma unroll
            for (int j = 0; j < 8; ++j) {
                int k = lane + (j << 6);
                acc += h1[k] * fw2[o*512 + k];
            }
#pragma unroll
            for (int m = 1; m < 64; m <<= 1) acc += __shfl_xor(acc, m, 64);
            if (lane == 0) ast(&h2g[b*256 + o], fmaxf(acc + fb2[o], 0.0f));
        }
    }
    signal_flag(H2);                                       // 8 writers per batch
    if (blk >= 4) return;
    wait_flag(H2, 8);

    // ======================= Phase 5: head3 (proven) ========================
    {
        const int b = blk;
        const int lane = t & 63, w = t >> 6;
        float* h2 = (float*)smem;                  // 1 KB
        if (t < 256) h2[t] = ald(&h2g[b*256 + t]);
        __syncthreads();
        if (t < 256 && w < 3) {
            float acc = 0.0f;
#pragma unroll
            for (int j = 0; j < 4; ++j) {
                int k = lane + (j << 6);
                acc += h2[k] * fw3[w*256 + k];
            }
#pragma unroll
            for (int m = 1; m < 64; m <<= 1) acc += __shfl_xor(acc, m, 64);
            if (lane == 0) out[b*3 + w] = acc + fb3[w];
        }
    }
}

extern "C" void kernel_launch(void* const* d_in, const int* in_sizes, int n_in,
                              void* d_out, int out_size, void* d_ws, size_t ws_size,
                              hipStream_t stream)
{
    const float* x    = (const float*)d_in[0];
    const int*   far0 = (const int*)  d_in[1];
    const float *w1 = (const float*)d_in[2],  *b1 = (const float*)d_in[3];
    const float *w2 = (const float*)d_in[4],  *b2 = (const float*)d_in[5];
    const float *w3 = (const float*)d_in[6],  *b3 = (const float*)d_in[7];
    const float *w4 = (const float*)d_in[8],  *b4 = (const float*)d_in[9];
    const float *w5 = (const float*)d_in[10], *b5 = (const float*)d_in[11];
    const float *fw1 = (const float*)d_in[12], *fb1 = (const float*)d_in[13];
    const float *fw2 = (const float*)d_in[14], *fb2 = (const float*)d_in[15];
    const float *fw3 = (const float*)d_in[16], *fb3 = (const float*)d_in[17];

    char* ws = (char*)d_ws;
    int*      ccount = (int*)     (ws + OFF_CCOUNT);
    int*      scount = (int*)     (ws + OFF_SCOUNT);
    unsigned* sbits  = (unsigned*)(ws + OFF_SBITS);
    float*    pool   = (float*)   (ws + OFF_POOL);
    int*      clist  = (int*)     (ws + OFF_CLIST);
    float*    h1g    = (float*)   (ws + OFF_H1);
    float*    h2g    = (float*)   (ws + OFF_H2);
    int*      slist  = (int*)     (ws + OFF_SLIST);
    unsigned* bar    = (unsigned*)(ws + OFF_BAR);

    // Flag counters must be zero (workspace is poisoned each iteration).
    (void)hipMemsetAsync(bar, 0, 20 * 16 * sizeof(unsigned), stream);
    mega_kernel<<<NBLK, 1024, 0, stream>>>(x, far0,
        w1,b1, w2,b2, w3,b3, w4,b4, w5,b5, fw1,fb1, fw2,fb2, fw3,fb3,
        clist, ccount, scount, sbits, slist, pool, h1g, h2g, (float*)d_out, bar);
}

// Round 9
// 169.489 us; speedup vs baseline: 1.1280x; 1.1280x over previous
//
#include <hip/hip_runtime.h>

// Problem constants (fixed by setup_inputs / reference)
#define BN  4       // batch
#define NPT 16384   // points per batch
#define NCC 1024    // FPS centroids (cap on unique orbit length)
#define KNN 32      // neighbors

// KNN select parameters
#define HBINS    2048   // 11-bit level-1 histogram
#define CCH      2      // centroids per chunk-block (keys fit in regs)
#define CAND_CAP 768    // boundary-bin candidate cap (overflow -> exact drill)

#define NBLK 64         // fused-kernel grid (all co-resident on 256 CUs)

// Workspace layout (bytes). ~310 KB + barrier counters.
#define OFF_CCOUNT 0                          // BN ints
#define OFF_SCOUNT 64                         // BN ints
#define OFF_SBITS  128                        // BN*(NPT/32) u32 = 8 KB
#define OFF_POOL   (128 + BN*(NPT/32)*4)      // BN*NCC floats = 16 KB
#define OFF_CLIST  (OFF_POOL + BN*NCC*4)      // BN*NCC ints = 16 KB
#define OFF_H1     (OFF_CLIST + BN*NCC*4)     // BN*512 floats = 8 KB
#define OFF_H2     (OFF_H1 + BN*512*4)        // BN*256 floats = 4 KB
#define OFF_SLIST  (OFF_H2 + BN*256*4)        // BN*NPT ints = 256 KB
#define OFF_BAR    (OFF_SLIST + BN*NPT*4)     // 45 counters x 64B = 2880 B

typedef short bf16x8 __attribute__((ext_vector_type(8)));
typedef float f32x4  __attribute__((ext_vector_type(4)));
typedef float f32x2  __attribute__((ext_vector_type(2)));

__device__ __forceinline__ short f2bf(float f) {   // RNE fp32 -> bf16
    unsigned u = __float_as_uint(f);
    return (short)((u + 0x7fffu + ((u >> 16) & 1u)) >> 16);
}
__device__ __forceinline__ bf16x8 cvt8(const float* __restrict__ p) {
    bf16x8 v;
#pragma unroll
    for (int j = 0; j < 8; ++j) v[j] = f2bf(p[j]);
    return v;
}

// ---------------------------------------------------------------------------
// Cross-block transport: every word that crosses a block boundary moves as a
// RELAXED AGENT-scope atomic (sc1 -> coherence point). No fences needed.
// ---------------------------------------------------------------------------
template <typename T>
__device__ __forceinline__ void ast(T* p, T v) {
    __hip_atomic_store(p, v, __ATOMIC_RELAXED, __HIP_MEMORY_SCOPE_AGENT);
}
template <typename T>
__device__ __forceinline__ T ald(const T* p) {
    return __hip_atomic_load(const_cast<T*>(p), __ATOMIC_RELAXED, __HIP_MEMORY_SCOPE_AGENT);
}

// ---------------------------------------------------------------------------
// Grid barrier v4: two-level tree, LOCKSTEP (R7/R8 lesson: desynchronized
// sync schemes cost ~35-40us in poll/coherence traffic; lockstep R5 = best).
//  - arrivals: 64 leaders fetch_add spread over 8 sub-counters on 8 SEPARATE
//    64B lines (8 RMWs/line in parallel vs R5's 64 on one line)
//  - block 0's leader aggregates the 8 sublines, then writes a write-once
//    'go' word on its OWN line
//  - 63 leaders poll only 'go': read-only polls on an RMW-free line; waits
//    are short because phases stay lockstep
// Layout: arrival(ph,s) = bar[(ph*8+s)*16]; go(ph) = bar[(40+ph)*16].
// signal's __syncthreads drains vmcnt => sc1 data committed before arrival.
// ---------------------------------------------------------------------------
__device__ __forceinline__ void gridbar(unsigned* __restrict__ bar, int ph) {
    __syncthreads();                                   // sc1 ops committed
    const int blk = blockIdx.x;
    if (threadIdx.x == 0) {
        unsigned* arr = bar + (ph*8 + (blk & 7)) * 16;
        unsigned* go  = bar + (40 + ph) * 16;
        __hip_atomic_fetch_add(arr, 1u, __ATOMIC_RELAXED, __HIP_MEMORY_SCOPE_AGENT);
        if (blk == 0) {
            for (int s = 0; s < 8; ++s) {              // master: gather sublines
                unsigned* a = bar + (ph*8 + s) * 16;
                while (__hip_atomic_load(a, __ATOMIC_RELAXED,
                                         __HIP_MEMORY_SCOPE_AGENT) < 8u)
                    __builtin_amdgcn_s_sleep(1);
            }
            ast(go, 1u);                               // broadcast
        } else {
            while (__hip_atomic_load(go, __ATOMIC_RELAXED,
                                     __HIP_MEMORY_SCOPE_AGENT) == 0u)
                __builtin_amdgcn_s_sleep(1);
        }
    }
    __syncthreads();                                   // broadcast within block
}

__device__ __forceinline__ unsigned key_of(float px, float py, float pz, float xn,
                                           float cx, float cy, float cz, float cn)
{
    float dot = __fadd_rn(__fadd_rn(__fmul_rn(cx,px), __fmul_rn(cy,py)), __fmul_rn(cz,pz));
    float d2  = __fsub_rn(__fadd_rn(cn, xn), __fmul_rn(2.0f, dot));
    unsigned u = __float_as_uint(d2);
    return u ^ ((u >> 31) ? 0xFFFFFFFFu : 0x80000000u);
}

__device__ __forceinline__ void wave_scan_bins(const unsigned* __restrict__ H,
    int nbins, int rem, int lane, int* __restrict__ out_bin, int* __restrict__ out_below)
{
    int per = nbins >> 6;
    int base = lane * per;
    unsigned part = 0;
    for (int q = 0; q < per; ++q) part += H[base + q];
    unsigned inc = part;
#pragma unroll
    for (int m = 1; m < 64; m <<= 1) {
        unsigned u = __shfl_up(inc, m, 64);
        if (lane >= m) inc += u;
    }
    unsigned exc = inc - part;
    unsigned long long mk = __ballot(exc < (unsigned)rem && inc >= (unsigned)rem);
    int src = __ffsll((long long)mk) - 1;
    if (lane == src) {
        unsigned run = exc; int bb = base;
        for (int q = 0; q < per; ++q) {
            unsigned h = H[base + q];
            if (run + h >= (unsigned)rem) { bb = base + q; break; }
            run += h;
        }
        *out_bin = bb; *out_below = (int)run;
    }
}

#define MFMA16(a, bfr, c) __builtin_amdgcn_mfma_f32_16x16x32_bf16(a, bfr, c, 0, 0, 0)

// ---------------------------------------------------------------------------
// Fused pipeline: FPS(v7) -> KNN(v5) -> MLP(v4) -> head1 -> head2 -> head3.
// Phase bodies and block->work maps byte-identical to R5's proven 72us
// kernel; ONLY the barrier implementation changed (v3 -> v4 tree).
// ---------------------------------------------------------------------------
__global__ __launch_bounds__(1024) void mega_kernel(const float* __restrict__ x,
    const int* __restrict__ far_init,
    const float* __restrict__ w1, const float* __restrict__ b1,
    const float* __restrict__ w2, const float* __restrict__ b2,
    const float* __restrict__ w3, const float* __restrict__ b3,
    const float* __restrict__ w4, const float* __restrict__ b4,
    const float* __restrict__ w5, const float* __restrict__ b5,
    const float* __restrict__ fw1, const float* __restrict__ fb1,
    const float* __restrict__ fw2, const float* __restrict__ fb2,
    const float* __restrict__ fw3, const float* __restrict__ fb3,
    int* __restrict__ clist, int* __restrict__ ccount, int* __restrict__ scount,
    unsigned* __restrict__ sbits, int* __restrict__ slist, float* __restrict__ pool,
    float* __restrict__ h1g, float* __restrict__ h2g, float* __restrict__ out,
    unsigned* __restrict__ bar)
{
    const int blk = blockIdx.x, t = threadIdx.x;
    // LDS overlay: max(FPS 16.6K, KNN 22.6K, MLP 36.6K, heads 4K)
    __shared__ __align__(16) char smem[36864];

    // ============ Phase 0: FPS (v7, absmax-0.0-verified R1/R5) ==============
    {
#pragma clang fp contract(off)
        if (blk < 4) {
            const int b = blk;
            unsigned char* seen   = (unsigned char*)smem;
            unsigned*      vslot  = (unsigned*)(smem + 16384);
            int*           islot  = (int*)(smem + 16384 + 8);
            int*           nmatch = (int*)(smem + 16384 + 16);
            int4*          cslot  = (int4*)(smem + 16384 + 32);  // [2][4]

            // ---- workspace zeroing for this batch (sc1: visible to all) ----
            if (t < 512) ast(&sbits[b*(NPT/32) + t], 0u);  // 512 u32
            ast(&pool[b*NCC + t], 0.0f);                   // 1024 floats
            if (t == 0) { ast(&ccount[b], 0); ast(&scount[b], 0); }

            const float* xb = x + (size_t)b * NPT * 3;
            f32x2 px[8], py[8], pz[8];
#pragma unroll
            for (int r = 0; r < 8; ++r) {
                int ia = t + ((2*r) << 10), ib = ia + 1024;
                px[r] = f32x2{xb[ia*3+0], xb[ib*3+0]};
                py[r] = f32x2{xb[ia*3+1], xb[ib*3+1]};
                pz[r] = f32x2{xb[ia*3+2], xb[ib*3+2]};
            }
            ((uint4*)seen)[t] = make_uint4(0,0,0,0);      // 1024 * 16B = 16 KB
            if (t == 0) {
                vslot[0] = 0u;         vslot[1] = 0u;
                islot[0] = 0x7fffffff; islot[1] = 0x7fffffff;
                nmatch[0] = 0;         nmatch[1] = 0;
            }
            int prev_bx = far_init[b];                    // uniform
            __syncthreads();
            int pbs = __builtin_amdgcn_readfirstlane(prev_bx);
            float cx = xb[pbs*3], cy = xb[pbs*3+1], cz = xb[pbs*3+2];

            int done = 0;
            for (int it = 0; it < NCC-1; ++it) {
                const int p = it & 1;
                const f32x2 cX = {cx, cx}, cY = {cy, cy}, cZ = {cz, cz};
                f32x2 sv[8];
                f32x2 rm = {0.0f, 0.0f};                  // distances >= 0
#pragma unroll
                for (int r = 0; r < 8; ++r) {
                    f32x2 dx = px[r] - cX;
                    f32x2 dy = py[r] - cY;
                    f32x2 dz = pz[r] - cZ;
                    f32x2 m1 = dx * dx;
                    f32x2 m2 = dy * dy;
                    f32x2 m3 = dz * dz;
                    f32x2 s  = (m1 + m2) + m3;            // exact grouping of reference
                    sv[r] = s;
                    rm.x = fmaxf(rm.x, s.x);
                    rm.y = fmaxf(rm.y, s.y);
                }
                float tm = fmaxf(rm.x, rm.y);
#pragma unroll
                for (int m = 1; m < 64; m <<= 1)
                    tm = fmaxf(tm, __shfl_xor(tm, m, 64)); // wave-uniform max
                if ((t & 63) == 0) atomicMax(&vslot[p], __float_as_uint(tm));
                if (t == 0) seen[prev_bx] = 1;            // pre-barrier write
                __syncthreads();                          // B1: block max final
                const unsigned bmax = vslot[p];
                if (t == 0) {                             // prep other parity
                    vslot[p^1] = 0u; islot[p^1] = 0x7fffffff; nmatch[p^1] = 0;
                }
                if (__float_as_uint(tm) == bmax) {        // wave-uniform: ~1/16 waves
                    int   myidx = 0x7fffffff;
                    float mx = 0.f, my = 0.f, mz = 0.f;
#pragma unroll
                    for (int r = 0; r < 8; ++r) {
                        int ia = t + ((2*r) << 10);
                        if (__float_as_uint(sv[r].x) == bmax && ia < myidx)
                            { myidx = ia;        mx = px[r].x; my = py[r].x; mz = pz[r].x; }
                        if (__float_as_uint(sv[r].y) == bmax && ia + 1024 < myidx)
                            { myidx = ia + 1024; mx = px[r].y; my = py[r].y; mz = pz[r].y; }
                    }
                    if (myidx != 0x7fffffff) {
                        atomicMin(&islot[p], myidx);      // first-index tie-break
                        int cs = atomicAdd(&nmatch[p], 1);
                        if (cs < 4)
                            cslot[p*4 + cs] = make_int4(myidx, __float_as_int(mx),
                                                        __float_as_int(my), __float_as_int(mz));
                    }
                }
                __syncthreads();                          // B2: winner final
                const int bx = islot[p];
                if (seen[bx]) { done = 1; break; }        // uniform
                prev_bx = bx;
                const int nm = nmatch[p] < 4 ? nmatch[p] : 4;
                bool got = false;
                float nx = 0.f, ny = 0.f, nz = 0.f;
#pragma unroll
                for (int csi = 0; csi < 4; ++csi) {       // LDS broadcast
                    if (csi < nm) {
                        int4 v = cslot[p*4 + csi];
                        if (v.x == bx) {
                            nx = __int_as_float(v.y); ny = __int_as_float(v.z);
                            nz = __int_as_float(v.w); got = true;
                        }
                    }
                }
                if (got) { cx = nx; cy = ny; cz = nz; }   // no L2 round-trip
                else {                                    // tie/overflow fallback
                    int bxs = __builtin_amdgcn_readfirstlane(bx);
                    cx = xb[bxs*3]; cy = xb[bxs*3+1]; cz = xb[bxs*3+2];
                }
            }
            if (!done && t == 0) seen[prev_bx] = 1;       // full orbit: mark last
            __syncthreads();
#pragma unroll
            for (int j = 0; j < 16; ++j) {
                int idx = t + (j << 10);
                if (seen[idx]) {
                    int pos = atomicAdd(&ccount[b], 1);
                    ast(&clist[b * NCC + pos], idx);
                }
            }
        }
    }
    gridbar(bar, 0);

    // ======================= Phase 1: KNN (v5, proven) ======================
    {
        const int c0 = ald(&ccount[0]), c1 = ald(&ccount[1]);
        const int c2 = ald(&ccount[2]), c3 = ald(&ccount[3]);
        const int maxc = max(max(c0,c1), max(c2,c3));
        unsigned* hist    = (unsigned*)smem;               // 16384 B
        unsigned* cand    = (unsigned*)(smem + 16384);     // 6144 B
        float*    cpx     = (float*)(smem + 22528);
        float*    cpy     = cpx + CCH;
        float*    cpz     = cpy + CCH;
        float*    cpn     = cpz + CCH;
        unsigned* candCnt = (unsigned*)(cpn + CCH);
        int*      s_bb    = (int*)(candCnt + CCH);
        int*      s_below = s_bb + CCH;
        int*      s_rrem  = s_below + CCH;
        int*      s_need  = s_rrem + CCH;
        int*      s_pref  = s_need + CCH;
        unsigned* s_tau   = (unsigned*)(s_pref + CCH);
        int*      s_tb    = (int*)(s_tau + CCH);           // [0]=tbin [1]=tbelow

        const int lane = t & 63, w = t >> 6;

        for (int wi = blk; (wi >> 2) * CCH < maxc; wi += NBLK) {
            const int b = wi & 3;
            const int cnt = (b==0) ? c0 : (b==1) ? c1 : (b==2) ? c2 : c3;
            const int cbase = (wi >> 2) * CCH;
            if (cbase >= cnt) continue;                    // block-uniform
            const float* xb = x + (size_t)b * NPT * 3;

            __syncthreads();                               // defensive item fence
            if (t < CCH) {
                int ci = ald(&clist[b * NCC + min(cbase + t, cnt - 1)]);  // tail-clamp dup
                float cx = xb[ci*3], cy = xb[ci*3+1], cz = xb[ci*3+2];
                cpx[t] = cx; cpy[t] = cy; cpz[t] = cz;
                cpn[t] = __fadd_rn(__fadd_rn(__fmul_rn(cx,cx), __fmul_rn(cy,cy)), __fmul_rn(cz,cz));
                candCnt[t] = 0;
            }
            for (int i = t; i < CCH * HBINS; i += 1024) hist[i] = 0;
            __syncthreads();

            // Sweep 1: compute keys ONCE into registers + build histograms.
            unsigned keys[NPT/1024][CCH];                  // 16 x 2 u32 = 32 VGPRs
#pragma unroll
            for (int j = 0; j < NPT/1024; ++j) {
                int i = t + (j << 10);
                float px = xb[i*3], py = xb[i*3+1], pz = xb[i*3+2];
                float xn = __fadd_rn(__fadd_rn(__fmul_rn(px,px), __fmul_rn(py,py)), __fmul_rn(pz,pz));
#pragma unroll
                for (int c = 0; c < CCH; ++c) {
                    unsigned key = key_of(px,py,pz,xn, cpx[c],cpy[c],cpz[c],cpn[c]);
                    keys[j][c] = key;
                    atomicAdd(&hist[c*HBINS + (key >> 21)], 1u);
                }
            }
            __syncthreads();

            if (w < CCH)
                wave_scan_bins(&hist[w*HBINS], HBINS, KNN, lane, &s_bb[w], &s_below[w]);
            __syncthreads();
            if (t < CCH) s_rrem[t] = KNN - s_below[t];
            __syncthreads();

            // Sweep 2 (registers only): collect candidate keys in boundary bins.
#pragma unroll
            for (int j = 0; j < NPT/1024; ++j) {
#pragma unroll
                for (int c = 0; c < CCH; ++c) {
                    unsigned key = keys[j][c];
                    if ((int)(key >> 21) == s_bb[c]) {
                        unsigned pos = atomicAdd(&candCnt[c], 1u);
                        if (pos < CAND_CAP) cand[c*CAND_CAP + pos] = key;
                    }
                }
            }
            __syncthreads();

            // Exact tau: rank-select per wave.
            if (w < CCH) {
                unsigned cc = candCnt[w];
                if (cc <= CAND_CAP) {
                    int r = s_rrem[w] - 1;
                    const unsigned* C = &cand[w*CAND_CAP];
                    for (int idx = lane; idx < (int)cc; idx += 64) {
                        unsigned k = C[idx]; int rank = 0;
                        for (int q = 0; q < (int)cc; ++q) {
                            unsigned kq = C[q];
                            rank += (kq < k || (kq == k && q < idx)) ? 1 : 0;
                        }
                        if (rank == r) s_tau[w] = k;
                    }
                    if (lane == 0) s_need[w] = 0;
                } else if (lane == 0) s_need[w] = 1;
            }
            __syncthreads();

            // Rare exact drill-down for overflowed boundary bins.
            for (int c = 0; c < CCH; ++c) {
                if (s_need[c]) {
                    const float cx = cpx[c], cy = cpy[c], cz = cpz[c], cn = cpn[c];
                    for (int i = t; i < HBINS; i += 1024) hist[i] = 0;
                    __syncthreads();
                    for (int j = 0; j < NPT/1024; ++j) {
                        int i = t + (j << 10);
                        float px = xb[i*3], py = xb[i*3+1], pz = xb[i*3+2];
                        float xn = __fadd_rn(__fadd_rn(__fmul_rn(px,px), __fmul_rn(py,py)), __fmul_rn(pz,pz));
                        unsigned key = key_of(px,py,pz,xn, cx,cy,cz,cn);
                        if ((int)(key >> 21) == s_bb[c]) atomicAdd(&hist[(key >> 10) & 2047u], 1u);
                    }
                    __syncthreads();
                    if (w == 0) wave_scan_bins(hist, HBINS, s_rrem[c], lane, &s_tb[0], &s_tb[1]);
                    __syncthreads();
                    if (t == 0) { s_pref[c] = (s_bb[c] << 11) | s_tb[0]; s_rrem[c] -= s_tb[1]; }
                    __syncthreads();
                    for (int i = t; i < 1024; i += 1024) hist[i] = 0;
                    __syncthreads();
                    for (int j = 0; j < NPT/1024; ++j) {
                        int i = t + (j << 10);
                        float px = xb[i*3], py = xb[i*3+1], pz = xb[i*3+2];
                        float xn = __fadd_rn(__fadd_rn(__fmul_rn(px,px), __fmul_rn(py,py)), __fmul_rn(pz,pz));
                        unsigned key = key_of(px,py,pz,xn, cx,cy,cz,cn);
                        if ((int)(key >> 10) == s_pref[c]) atomicAdd(&hist[key & 1023u], 1u);
                    }
                    __syncthreads();
                    if (w == 0) wave_scan_bins(hist, 1024, s_rrem[c], lane, &s_tb[0], &s_tb[1]);
                    __syncthreads();
                    if (t == 0) s_tau[c] = (((unsigned)s_pref[c]) << 10) | (unsigned)s_tb[0];
                    __syncthreads();
                }
            }
            __syncthreads();

            // Sweep 3 (registers only): union-mark + build compacted list (deduped).
#pragma unroll
            for (int j = 0; j < NPT/1024; ++j) {
                int i = t + (j << 10);
                bool sel = false;
#pragma unroll
                for (int c = 0; c < CCH; ++c) sel |= (keys[j][c] <= s_tau[c]);
                if (sel) {
                    unsigned bit = 1u << (i & 31);
                    unsigned old = atomicOr(&sbits[b*(NPT/32) + (i >> 5)], bit);
                    if (!(old & bit)) {
                        int pos = atomicAdd(&scount[b], 1);
                        ast(&slist[b * NPT + pos], i);
                    }
                }
            }
        }
    }
    gridbar(bar, 1);

    // ======================= Phase 2: MLP (v4, proven) ======================
    {
        const int s0 = ald(&scount[0]), s1 = ald(&scount[1]);
        const int s2 = ald(&scount[2]), s3 = ald(&scount[3]);
        short* A1 = (short*)smem;                 // 64*72*2 = 9216
        short* A2 = (short*)(smem + 9216);        // 9216
        short* A3 = (short*)(smem + 18432);       // 64*136*2 = 17408
        float* sx = (float*)(smem + 35840);       // 3*64*4 = 768

        const int lane = t & 63;
        const int w    = __builtin_amdgcn_readfirstlane(t >> 6);  // 0..15
        const int m    = lane & 15, quad = lane >> 4;
        const int b    = blk & 3;                 // block-constant batch
        const int z    = (blk >> 2) & 3;          // block-constant oc5 slice
        const int cnt  = (b==0) ? s0 : (b==1) ? s1 : (b==2) ? s2 : s3;

        // hoisted weight fragments (block-constant)
        const int ocA = (w >> 2) * 16 + m;
        bf16x8 bw2[2], bw3[2], bw4[2][2], bw5[4];
#pragma unroll
        for (int ks = 0; ks < 2; ++ks) {
            bw2[ks] = cvt8(w2 + ocA*64 + ks*32 + quad*8);
            bw3[ks] = cvt8(w3 + ocA*64 + ks*32 + quad*8);
        }
        int oc4i[2];
#pragma unroll
        for (int r2 = 0; r2 < 2; ++r2) {
            oc4i[r2] = ((w >> 2) + 4*r2) * 16 + m;
#pragma unroll
            for (int ks = 0; ks < 2; ++ks)
                bw4[r2][ks] = cvt8(w4 + oc4i[r2]*64 + ks*32 + quad*8);
        }
        const int oc5 = z*256 + w*16 + m;
#pragma unroll
        for (int ks = 0; ks < 4; ++ks)
            bw5[ks] = cvt8(w5 + oc5*128 + ks*32 + quad*8);
        const float bias2 = b2[ocA], bias3 = b3[ocA];
        const float bias4_0 = b4[oc4i[0]], bias4_1 = b4[oc4i[1]];
        const float bias5 = b5[oc5];
        float w1v[4][3], b1v[4];
#pragma unroll
        for (int i = 0; i < 4; ++i) {
            int oc = w*4 + i;
            w1v[i][0] = w1[oc*3+0]; w1v[i][1] = w1[oc*3+1]; w1v[i][2] = w1[oc*3+2];
            b1v[i] = b1[oc];
        }
        const int pt0 = (w & 3) * 16;             // pt tile for L2/L3/L4

        for (int xblk = blk >> 4; xblk * 64 < cnt; xblk += 4) {
            const int base = xblk << 6;
            const int npts = min(64, cnt - base);
            __syncthreads();                       // prev tile fully consumed
            if (t < 64) {
                int idx = ald(&slist[b * NPT + base + min(t, npts - 1)]);  // pad = dup last
                const float* xp = x + ((size_t)b * NPT + idx) * 3;
                sx[t] = xp[0]; sx[64 + t] = xp[1]; sx[128 + t] = xp[2];
            }
            __syncthreads();
            {   // L1: 3->64, fp32 VALU, write bf16 [pt][72]
                float x0 = sx[lane], x1 = sx[64 + lane], x2 = sx[128 + lane];
#pragma unroll
                for (int i = 0; i < 4; ++i) {
                    float acc = fmaf(x2, w1v[i][2], fmaf(x1, w1v[i][1],
                                 fmaf(x0, w1v[i][0], b1v[i])));
                    A1[lane*72 + w*4 + i] = f2bf(fmaxf(acc, 0.0f));
                }
            }
            __syncthreads();
            {   // L2: A1 -> A2 (64->64)
                bf16x8 a0 = *(const bf16x8*)&A1[(pt0 + m)*72 + quad*8];
                bf16x8 a1 = *(const bf16x8*)&A1[(pt0 + m)*72 + 32 + quad*8];
                f32x4 d = {0.f, 0.f, 0.f, 0.f};
                d = MFMA16(a0, bw2[0], d);
                d = MFMA16(a1, bw2[1], d);
#pragma unroll
                for (int r = 0; r < 4; ++r)
                    A2[(pt0 + quad*4 + r)*72 + ocA] = f2bf(fmaxf(d[r] + bias2, 0.0f));
            }
            __syncthreads();
            {   // L3: A2 -> A1 (64->64)
                bf16x8 a0 = *(const bf16x8*)&A2[(pt0 + m)*72 + quad*8];
                bf16x8 a1 = *(const bf16x8*)&A2[(pt0 + m)*72 + 32 + quad*8];
                f32x4 d = {0.f, 0.f, 0.f, 0.f};
                d = MFMA16(a0, bw3[0], d);
                d = MFMA16(a1, bw3[1], d);
#pragma unroll
                for (int r = 0; r < 4; ++r)
                    A1[(pt0 + quad*4 + r)*72 + ocA] = f2bf(fmaxf(d[r] + bias3, 0.0f));
            }
            __syncthreads();
            {   // L4: A1 -> A3 (64->128), 2 oc-tiles per wave
                bf16x8 a0 = *(const bf16x8*)&A1[(pt0 + m)*72 + quad*8];
                bf16x8 a1 = *(const bf16x8*)&A1[(pt0 + m)*72 + 32 + quad*8];
#pragma unroll
                for (int r2 = 0; r2 < 2; ++r2) {
                    f32x4 d = {0.f, 0.f, 0.f, 0.f};
                    d = MFMA16(a0, bw4[r2][0], d);
                    d = MFMA16(a1, bw4[r2][1], d);
                    float bs = r2 ? bias4_1 : bias4_0;
#pragma unroll
                    for (int r = 0; r < 4; ++r)
                        A3[(pt0 + quad*4 + r)*136 + oc4i[r2]] = f2bf(fmaxf(d[r] + bs, 0.0f));
                }
            }
            __syncthreads();
            {   // L5 (128 -> this block's 256-oc slice) + max-pool
                float vm = 0.0f;                   // relu outputs >= 0
#pragma unroll
                for (int pt4 = 0; pt4 < 4; ++pt4) {
                    const int q0 = pt4 * 16;
                    f32x4 d = {0.f, 0.f, 0.f, 0.f};
#pragma unroll
                    for (int ks = 0; ks < 4; ++ks) {
                        bf16x8 a = *(const bf16x8*)&A3[(q0 + m)*136 + ks*32 + quad*8];
                        d = MFMA16(a, bw5[ks], d);
                    }
#pragma unroll
                    for (int r = 0; r < 4; ++r)
                        vm = fmaxf(vm, fmaxf(d[r] + bias5, 0.0f));
                }
                vm = fmaxf(vm, __shfl_xor(vm, 16, 64));
                vm = fmaxf(vm, __shfl_xor(vm, 32, 64));
                if (lane < 16)
                    atomicMax((int*)&pool[b*NCC + z*256 + w*16 + lane], __float_as_int(vm));
            }
        }
    }
    gridbar(bar, 2);

    // ======================= Phase 3: head1 (proven) ========================
    {
        const int bo = blk >> 2, b = blk & 3;      // 64 items: all blocks
        const int lane = t & 63, w = t >> 6;
        float* g = (float*)smem;                   // 4 KB
        g[t] = ald(&pool[b*NCC + t]);
        __syncthreads();
#pragma unroll
        for (int i = 0; i < 2; ++i) {
            int o = bo * 32 + w * 2 + i;
            float acc = 0.0f;
#pragma unroll
            for (int j = 0; j < 16; ++j) {
                int k = lane + (j << 6);
                acc += g[k] * fw1[o*1024 + k];
            }
#pragma unroll
            for (int m = 1; m < 64; m <<= 1) acc += __shfl_xor(acc, m, 64);
            if (lane == 0) ast(&h1g[b*512 + o], fmaxf(acc + fb1[o], 0.0f));
        }
    }
    gridbar(bar, 3);

    // ======================= Phase 4: head2 (proven) ========================
    if (blk < 32) {
        const int bo = blk >> 2, b = blk & 3;      // 32 items
        const int lane = t & 63, w = t >> 6;
        float* h1 = (float*)smem;                  // 2 KB
        if (t < 512) h1[t] = ald(&h1g[b*512 + t]);
        __syncthreads();
#pragma unroll
        for (int i = 0; i < 2; ++i) {
            int o = bo * 32 + w * 2 + i;
            float acc = 0.0f;
#pragma unroll
            for (int j = 0; j < 8; ++j) {
                int k = lane + (j << 6);
                acc += h1[k] * fw2[o*512 + k];
            }
#pragma unroll
            for (int m = 1; m < 64; m <<= 1) acc += __shfl_xor(acc, m, 64);
            if (lane == 0) ast(&h2g[b*256 + o], fmaxf(acc + fb2[o], 0.0f));
        }
    }
    gridbar(bar, 4);

    // ======================= Phase 5: head3 (proven) ========================
    if (blk < 4) {
        const int b = blk;
        const int lane = t & 63, w = t >> 6;
        float* h2 = (float*)smem;                  // 1 KB
        if (t < 256) h2[t] = ald(&h2g[b*256 + t]);
        __syncthreads();
        if (t < 256 && w < 3) {
            float acc = 0.0f;
#pragma unroll
            for (int j = 0; j < 4; ++j) {
                int k = lane + (j << 6);
                acc += h2[k] * fw3[w*256 + k];
            }
#pragma unroll
            for (int m = 1; m < 64; m <<= 1) acc += __shfl_xor(acc, m, 64);
            if (lane == 0) out[b*3 + w] = acc + fb3[w];
        }
    }
}

extern "C" void kernel_launch(void* const* d_in, const int* in_sizes, int n_in,
                              void* d_out, int out_size, void* d_ws, size_t ws_size,
                              hipStream_t stream)
{
    const float* x    = (const float*)d_in[0];
    const int*   far0 = (const int*)  d_in[1];
    const float *w1 = (const float*)d_in[2],  *b1 = (const float*)d_in[3];
    const float *w2 = (const float*)d_in[4],  *b2 = (const float*)d_in[5];
    const float *w3 = (const float*)d_in[6],  *b3 = (const float*)d_in[7];
    const float *w4 = (const float*)d_in[8],  *b4 = (const float*)d_in[9];
    const float *w5 = (const float*)d_in[10], *b5 = (const float*)d_in[11];
    const float *fw1 = (const float*)d_in[12], *fb1 = (const float*)d_in[13];
    const float *fw2 = (const float*)d_in[14], *fb2 = (const float*)d_in[15];
    const float *fw3 = (const float*)d_in[16], *fb3 = (const float*)d_in[17];

    char* ws = (char*)d_ws;
    int*      ccount = (int*)     (ws + OFF_CCOUNT);
    int*      scount = (int*)     (ws + OFF_SCOUNT);
    unsigned* sbits  = (unsigned*)(ws + OFF_SBITS);
    float*    pool   = (float*)   (ws + OFF_POOL);
    int*      clist  = (int*)     (ws + OFF_CLIST);
    float*    h1g    = (float*)   (ws + OFF_H1);
    float*    h2g    = (float*)   (ws + OFF_H2);
    int*      slist  = (int*)     (ws + OFF_SLIST);
    unsigned* bar    = (unsigned*)(ws + OFF_BAR);

    // Barrier counters must be zero (workspace is poisoned each iteration).
    (void)hipMemsetAsync(bar, 0, 45 * 16 * sizeof(unsigned), stream);
    mega_kernel<<<NBLK, 1024, 0, stream>>>(x, far0,
        w1,b1, w2,b2, w3,b3, w4,b4, w5,b5, fw1,fb1, fw2,fb2, fw3,fb3,
        clist, ccount, scount, sbits, slist, pool, h1g, h2g, (float*)d_out, bar);
}

// Round 10
// 164.018 us; speedup vs baseline: 1.1656x; 1.0334x over previous
//
#include <hip/hip_runtime.h>

// Problem constants (fixed by setup_inputs / reference)
#define BN  4       // batch
#define NPT 16384   // points per batch
#define NCC 1024    // FPS centroids (cap on unique orbit length)
#define KNN 32      // neighbors

// KNN select parameters
#define HBINS    2048   // 11-bit level-1 histogram
#define CCH      2      // centroids per chunk-block (keys fit in regs)
#define CAND_CAP 768    // boundary-bin candidate cap (overflow -> exact drill)

#define NBLK 64         // fused-kernel grid (all co-resident on 256 CUs)

// Workspace layout (bytes). ~310 KB + barrier counters.
#define OFF_CCOUNT 0                          // BN ints
#define OFF_SCOUNT 64                         // BN ints
#define OFF_SBITS  128                        // BN*(NPT/32) u32 = 8 KB
#define OFF_POOL   (128 + BN*(NPT/32)*4)      // BN*NCC floats = 16 KB
#define OFF_CLIST  (OFF_POOL + BN*NCC*4)      // BN*NCC ints = 16 KB
#define OFF_H1     (OFF_CLIST + BN*NCC*4)     // BN*512 floats = 8 KB
#define OFF_H2     (OFF_H1 + BN*512*4)        // BN*256 floats = 4 KB
#define OFF_SLIST  (OFF_H2 + BN*256*4)        // BN*NPT ints = 256 KB
#define OFF_BAR    (OFF_SLIST + BN*NPT*4)     // 8 u32 barrier counters

typedef short bf16x8 __attribute__((ext_vector_type(8)));
typedef float f32x4  __attribute__((ext_vector_type(4)));
typedef float f32x2  __attribute__((ext_vector_type(2)));

__device__ __forceinline__ short f2bf(float f) {   // RNE fp32 -> bf16
    unsigned u = __float_as_uint(f);
    return (short)((u + 0x7fffu + ((u >> 16) & 1u)) >> 16);
}
__device__ __forceinline__ bf16x8 cvt8(const float* __restrict__ p) {
    bf16x8 v;
#pragma unroll
    for (int j = 0; j < 8; ++j) v[j] = f2bf(p[j]);
    return v;
}

// ---------------------------------------------------------------------------
// Cross-block transport: every word that crosses a block boundary moves as a
// RELAXED AGENT-scope atomic (sc1 -> coherence point). No fences needed.
// ---------------------------------------------------------------------------
template <typename T>
__device__ __forceinline__ void ast(T* p, T v) {
    __hip_atomic_store(p, v, __ATOMIC_RELAXED, __HIP_MEMORY_SCOPE_AGENT);
}
template <typename T>
__device__ __forceinline__ T ald(const T* p) {
    return __hip_atomic_load(const_cast<T*>(p), __ATOMIC_RELAXED, __HIP_MEMORY_SCOPE_AGENT);
}

// ---------------------------------------------------------------------------
// Grid barrier v3 (R5-proven best: single line, lockstep, relaxed read poll).
// R7/R8/R9 falsified per-group, producer-consumer, and 8-line-tree variants
// (+26..+40us each): do NOT add atomic lines or desynchronize.
// Split form (arrive/wait) lets callers overlap pure-read preloads with the
// wait window; arrive's __syncthreads drains vmcnt => sc1 data committed
// before the flag increments (same ordering as the fused v3).
// ---------------------------------------------------------------------------
__device__ __forceinline__ void gb_arrive(unsigned* __restrict__ bar, int ph) {
    __syncthreads();                                   // drains vmcnt: sc1 ops committed
    if (threadIdx.x == 0)
        __hip_atomic_fetch_add(&bar[ph], 1u, __ATOMIC_RELAXED, __HIP_MEMORY_SCOPE_AGENT);
}
__device__ __forceinline__ void gb_wait(unsigned* __restrict__ bar, int ph) {
    if (threadIdx.x == 0) {
        while (__hip_atomic_load(&bar[ph], __ATOMIC_RELAXED, __HIP_MEMORY_SCOPE_AGENT)
               < (unsigned)NBLK)
            __builtin_amdgcn_s_sleep(2);
    }
    __syncthreads();                                   // broadcast + drain preloads
}
__device__ __forceinline__ void gridbar(unsigned* __restrict__ bar, int ph) {
    gb_arrive(bar, ph);
    gb_wait(bar, ph);
}

__device__ __forceinline__ unsigned key_of(float px, float py, float pz, float xn,
                                           float cx, float cy, float cz, float cn)
{
    float dot = __fadd_rn(__fadd_rn(__fmul_rn(cx,px), __fmul_rn(cy,py)), __fmul_rn(cz,pz));
    float d2  = __fsub_rn(__fadd_rn(cn, xn), __fmul_rn(2.0f, dot));
    unsigned u = __float_as_uint(d2);
    return u ^ ((u >> 31) ? 0xFFFFFFFFu : 0x80000000u);
}

__device__ __forceinline__ void wave_scan_bins(const unsigned* __restrict__ H,
    int nbins, int rem, int lane, int* __restrict__ out_bin, int* __restrict__ out_below)
{
    int per = nbins >> 6;
    int base = lane * per;
    unsigned part = 0;
    for (int q = 0; q < per; ++q) part += H[base + q];
    unsigned inc = part;
#pragma unroll
    for (int m = 1; m < 64; m <<= 1) {
        unsigned u = __shfl_up(inc, m, 64);
        if (lane >= m) inc += u;
    }
    unsigned exc = inc - part;
    unsigned long long mk = __ballot(exc < (unsigned)rem && inc >= (unsigned)rem);
    int src = __ffsll((long long)mk) - 1;
    if (lane == src) {
        unsigned run = exc; int bb = base;
        for (int q = 0; q < per; ++q) {
            unsigned h = H[base + q];
            if (run + h >= (unsigned)rem) { bb = base + q; break; }
            run += h;
        }
        *out_bin = bb; *out_below = (int)run;
    }
}

#define MFMA16(a, bfr, c) __builtin_amdgcn_mfma_f32_16x16x32_bf16(a, bfr, c, 0, 0, 0)

// ---------------------------------------------------------------------------
// Fused pipeline: FPS(v7) -> KNN(v5) -> MLP(v4) -> head1 -> head2 -> head3.
// R5's proven 72us kernel, with ONE change: barriers 2 and 3 are split so
// head1's fw1-slice (32 regs) and head2's fw2-slice (16 regs) preload inside
// the barrier wait window (cold HBM stream overlaps wait-for-slowest; the
// critical-path block signals BEFORE preloading -- bounded ~1us downside).
// ---------------------------------------------------------------------------
__global__ __launch_bounds__(1024) void mega_kernel(const float* __restrict__ x,
    const int* __restrict__ far_init,
    const float* __restrict__ w1, const float* __restrict__ b1,
    const float* __restrict__ w2, const float* __restrict__ b2,
    const float* __restrict__ w3, const float* __restrict__ b3,
    const float* __restrict__ w4, const float* __restrict__ b4,
    const float* __restrict__ w5, const float* __restrict__ b5,
    const float* __restrict__ fw1, const float* __restrict__ fb1,
    const float* __restrict__ fw2, const float* __restrict__ fb2,
    const float* __restrict__ fw3, const float* __restrict__ fb3,
    int* __restrict__ clist, int* __restrict__ ccount, int* __restrict__ scount,
    unsigned* __restrict__ sbits, int* __restrict__ slist, float* __restrict__ pool,
    float* __restrict__ h1g, float* __restrict__ h2g, float* __restrict__ out,
    unsigned* __restrict__ bar)
{
    const int blk = blockIdx.x, t = threadIdx.x;
    // LDS overlay: max(FPS 16.6K, KNN 22.6K, MLP 36.6K, heads 4K)
    __shared__ __align__(16) char smem[36864];

    // ============ Phase 0: FPS (v7, absmax-0.0-verified R1/R5) ==============
    {
#pragma clang fp contract(off)
        if (blk < 4) {
            const int b = blk;
            unsigned char* seen   = (unsigned char*)smem;
            unsigned*      vslot  = (unsigned*)(smem + 16384);
            int*           islot  = (int*)(smem + 16384 + 8);
            int*           nmatch = (int*)(smem + 16384 + 16);
            int4*          cslot  = (int4*)(smem + 16384 + 32);  // [2][4]

            // ---- workspace zeroing for this batch (sc1: visible to all) ----
            if (t < 512) ast(&sbits[b*(NPT/32) + t], 0u);  // 512 u32
            ast(&pool[b*NCC + t], 0.0f);                   // 1024 floats
            if (t == 0) { ast(&ccount[b], 0); ast(&scount[b], 0); }

            const float* xb = x + (size_t)b * NPT * 3;
            f32x2 px[8], py[8], pz[8];
#pragma unroll
            for (int r = 0; r < 8; ++r) {
                int ia = t + ((2*r) << 10), ib = ia + 1024;
                px[r] = f32x2{xb[ia*3+0], xb[ib*3+0]};
                py[r] = f32x2{xb[ia*3+1], xb[ib*3+1]};
                pz[r] = f32x2{xb[ia*3+2], xb[ib*3+2]};
            }
            ((uint4*)seen)[t] = make_uint4(0,0,0,0);      // 1024 * 16B = 16 KB
            if (t == 0) {
                vslot[0] = 0u;         vslot[1] = 0u;
                islot[0] = 0x7fffffff; islot[1] = 0x7fffffff;
                nmatch[0] = 0;         nmatch[1] = 0;
            }
            int prev_bx = far_init[b];                    // uniform
            __syncthreads();
            int pbs = __builtin_amdgcn_readfirstlane(prev_bx);
            float cx = xb[pbs*3], cy = xb[pbs*3+1], cz = xb[pbs*3+2];

            int done = 0;
            for (int it = 0; it < NCC-1; ++it) {
                const int p = it & 1;
                const f32x2 cX = {cx, cx}, cY = {cy, cy}, cZ = {cz, cz};
                f32x2 sv[8];
                f32x2 rm = {0.0f, 0.0f};                  // distances >= 0
#pragma unroll
                for (int r = 0; r < 8; ++r) {
                    f32x2 dx = px[r] - cX;
                    f32x2 dy = py[r] - cY;
                    f32x2 dz = pz[r] - cZ;
                    f32x2 m1 = dx * dx;
                    f32x2 m2 = dy * dy;
                    f32x2 m3 = dz * dz;
                    f32x2 s  = (m1 + m2) + m3;            // exact grouping of reference
                    sv[r] = s;
                    rm.x = fmaxf(rm.x, s.x);
                    rm.y = fmaxf(rm.y, s.y);
                }
                float tm = fmaxf(rm.x, rm.y);
#pragma unroll
                for (int m = 1; m < 64; m <<= 1)
                    tm = fmaxf(tm, __shfl_xor(tm, m, 64)); // wave-uniform max
                if ((t & 63) == 0) atomicMax(&vslot[p], __float_as_uint(tm));
                if (t == 0) seen[prev_bx] = 1;            // pre-barrier write
                __syncthreads();                          // B1: block max final
                const unsigned bmax = vslot[p];
                if (t == 0) {                             // prep other parity
                    vslot[p^1] = 0u; islot[p^1] = 0x7fffffff; nmatch[p^1] = 0;
                }
                if (__float_as_uint(tm) == bmax) {        // wave-uniform: ~1/16 waves
                    int   myidx = 0x7fffffff;
                    float mx = 0.f, my = 0.f, mz = 0.f;
#pragma unroll
                    for (int r = 0; r < 8; ++r) {
                        int ia = t + ((2*r) << 10);
                        if (__float_as_uint(sv[r].x) == bmax && ia < myidx)
                            { myidx = ia;        mx = px[r].x; my = py[r].x; mz = pz[r].x; }
                        if (__float_as_uint(sv[r].y) == bmax && ia + 1024 < myidx)
                            { myidx = ia + 1024; mx = px[r].y; my = py[r].y; mz = pz[r].y; }
                    }
                    if (myidx != 0x7fffffff) {
                        atomicMin(&islot[p], myidx);      // first-index tie-break
                        int cs = atomicAdd(&nmatch[p], 1);
                        if (cs < 4)
                            cslot[p*4 + cs] = make_int4(myidx, __float_as_int(mx),
                                                        __float_as_int(my), __float_as_int(mz));
                    }
                }
                __syncthreads();                          // B2: winner final
                const int bx = islot[p];
                if (seen[bx]) { done = 1; break; }        // uniform
                prev_bx = bx;
                const int nm = nmatch[p] < 4 ? nmatch[p] : 4;
                bool got = false;
                float nx = 0.f, ny = 0.f, nz = 0.f;
#pragma unroll
                for (int csi = 0; csi < 4; ++csi) {       // LDS broadcast
                    if (csi < nm) {
                        int4 v = cslot[p*4 + csi];
                        if (v.x == bx) {
                            nx = __int_as_float(v.y); ny = __int_as_float(v.z);
                            nz = __int_as_float(v.w); got = true;
                        }
                    }
                }
                if (got) { cx = nx; cy = ny; cz = nz; }   // no L2 round-trip
                else {                                    // tie/overflow fallback
                    int bxs = __builtin_amdgcn_readfirstlane(bx);
                    cx = xb[bxs*3]; cy = xb[bxs*3+1]; cz = xb[bxs*3+2];
                }
            }
            if (!done && t == 0) seen[prev_bx] = 1;       // full orbit: mark last
            __syncthreads();
#pragma unroll
            for (int j = 0; j < 16; ++j) {
                int idx = t + (j << 10);
                if (seen[idx]) {
                    int pos = atomicAdd(&ccount[b], 1);
                    ast(&clist[b * NCC + pos], idx);
                }
            }
        }
    }
    gridbar(bar, 0);

    // ======================= Phase 1: KNN (v5, proven) ======================
    {
        const int c0 = ald(&ccount[0]), c1 = ald(&ccount[1]);
        const int c2 = ald(&ccount[2]), c3 = ald(&ccount[3]);
        const int maxc = max(max(c0,c1), max(c2,c3));
        unsigned* hist    = (unsigned*)smem;               // 16384 B
        unsigned* cand    = (unsigned*)(smem + 16384);     // 6144 B
        float*    cpx     = (float*)(smem + 22528);
        float*    cpy     = cpx + CCH;
        float*    cpz     = cpy + CCH;
        float*    cpn     = cpz + CCH;
        unsigned* candCnt = (unsigned*)(cpn + CCH);
        int*      s_bb    = (int*)(candCnt + CCH);
        int*      s_below = s_bb + CCH;
        int*      s_rrem  = s_below + CCH;
        int*      s_need  = s_rrem + CCH;
        int*      s_pref  = s_need + CCH;
        unsigned* s_tau   = (unsigned*)(s_pref + CCH);
        int*      s_tb    = (int*)(s_tau + CCH);           // [0]=tbin [1]=tbelow

        const int lane = t & 63, w = t >> 6;

        for (int wi = blk; (wi >> 2) * CCH < maxc; wi += NBLK) {
            const int b = wi & 3;
            const int cnt = (b==0) ? c0 : (b==1) ? c1 : (b==2) ? c2 : c3;
            const int cbase = (wi >> 2) * CCH;
            if (cbase >= cnt) continue;                    // block-uniform
            const float* xb = x + (size_t)b * NPT * 3;

            __syncthreads();                               // defensive item fence
            if (t < CCH) {
                int ci = ald(&clist[b * NCC + min(cbase + t, cnt - 1)]);  // tail-clamp dup
                float cx = xb[ci*3], cy = xb[ci*3+1], cz = xb[ci*3+2];
                cpx[t] = cx; cpy[t] = cy; cpz[t] = cz;
                cpn[t] = __fadd_rn(__fadd_rn(__fmul_rn(cx,cx), __fmul_rn(cy,cy)), __fmul_rn(cz,cz));
                candCnt[t] = 0;
            }
            for (int i = t; i < CCH * HBINS; i += 1024) hist[i] = 0;
            __syncthreads();

            // Sweep 1: compute keys ONCE into registers + build histograms.
            unsigned keys[NPT/1024][CCH];                  // 16 x 2 u32 = 32 VGPRs
#pragma unroll
            for (int j = 0; j < NPT/1024; ++j) {
                int i = t + (j << 10);
                float px = xb[i*3], py = xb[i*3+1], pz = xb[i*3+2];
                float xn = __fadd_rn(__fadd_rn(__fmul_rn(px,px), __fmul_rn(py,py)), __fmul_rn(pz,pz));
#pragma unroll
                for (int c = 0; c < CCH; ++c) {
                    unsigned key = key_of(px,py,pz,xn, cpx[c],cpy[c],cpz[c],cpn[c]);
                    keys[j][c] = key;
                    atomicAdd(&hist[c*HBINS + (key >> 21)], 1u);
                }
            }
            __syncthreads();

            if (w < CCH)
                wave_scan_bins(&hist[w*HBINS], HBINS, KNN, lane, &s_bb[w], &s_below[w]);
            __syncthreads();
            if (t < CCH) s_rrem[t] = KNN - s_below[t];
            __syncthreads();

            // Sweep 2 (registers only): collect candidate keys in boundary bins.
#pragma unroll
            for (int j = 0; j < NPT/1024; ++j) {
#pragma unroll
                for (int c = 0; c < CCH; ++c) {
                    unsigned key = keys[j][c];
                    if ((int)(key >> 21) == s_bb[c]) {
                        unsigned pos = atomicAdd(&candCnt[c], 1u);
                        if (pos < CAND_CAP) cand[c*CAND_CAP + pos] = key;
                    }
                }
            }
            __syncthreads();

            // Exact tau: rank-select per wave.
            if (w < CCH) {
                unsigned cc = candCnt[w];
                if (cc <= CAND_CAP) {
                    int r = s_rrem[w] - 1;
                    const unsigned* C = &cand[w*CAND_CAP];
                    for (int idx = lane; idx < (int)cc; idx += 64) {
                        unsigned k = C[idx]; int rank = 0;
                        for (int q = 0; q < (int)cc; ++q) {
                            unsigned kq = C[q];
                            rank += (kq < k || (kq == k && q < idx)) ? 1 : 0;
                        }
                        if (rank == r) s_tau[w] = k;
                    }
                    if (lane == 0) s_need[w] = 0;
                } else if (lane == 0) s_need[w] = 1;
            }
            __syncthreads();

            // Rare exact drill-down for overflowed boundary bins.
            for (int c = 0; c < CCH; ++c) {
                if (s_need[c]) {
                    const float cx = cpx[c], cy = cpy[c], cz = cpz[c], cn = cpn[c];
                    for (int i = t; i < HBINS; i += 1024) hist[i] = 0;
                    __syncthreads();
                    for (int j = 0; j < NPT/1024; ++j) {
                        int i = t + (j << 10);
                        float px = xb[i*3], py = xb[i*3+1], pz = xb[i*3+2];
                        float xn = __fadd_rn(__fadd_rn(__fmul_rn(px,px), __fmul_rn(py,py)), __fmul_rn(pz,pz));
                        unsigned key = key_of(px,py,pz,xn, cx,cy,cz,cn);
                        if ((int)(key >> 21) == s_bb[c]) atomicAdd(&hist[(key >> 10) & 2047u], 1u);
                    }
                    __syncthreads();
                    if (w == 0) wave_scan_bins(hist, HBINS, s_rrem[c], lane, &s_tb[0], &s_tb[1]);
                    __syncthreads();
                    if (t == 0) { s_pref[c] = (s_bb[c] << 11) | s_tb[0]; s_rrem[c] -= s_tb[1]; }
                    __syncthreads();
                    for (int i = t; i < 1024; i += 1024) hist[i] = 0;
                    __syncthreads();
                    for (int j = 0; j < NPT/1024; ++j) {
                        int i = t + (j << 10);
                        float px = xb[i*3], py = xb[i*3+1], pz = xb[i*3+2];
                        float xn = __fadd_rn(__fadd_rn(__fmul_rn(px,px), __fmul_rn(py,py)), __fmul_rn(pz,pz));
                        unsigned key = key_of(px,py,pz,xn, cx,cy,cz,cn);
                        if ((int)(key >> 10) == s_pref[c]) atomicAdd(&hist[key & 1023u], 1u);
                    }
                    __syncthreads();
                    if (w == 0) wave_scan_bins(hist, 1024, s_rrem[c], lane, &s_tb[0], &s_tb[1]);
                    __syncthreads();
                    if (t == 0) s_tau[c] = (((unsigned)s_pref[c]) << 10) | (unsigned)s_tb[0];
                    __syncthreads();
                }
            }
            __syncthreads();

            // Sweep 3 (registers only): union-mark + build compacted list (deduped).
#pragma unroll
            for (int j = 0; j < NPT/1024; ++j) {
                int i = t + (j << 10);
                bool sel = false;
#pragma unroll
                for (int c = 0; c < CCH; ++c) sel |= (keys[j][c] <= s_tau[c]);
                if (sel) {
                    unsigned bit = 1u << (i & 31);
                    unsigned old = atomicOr(&sbits[b*(NPT/32) + (i >> 5)], bit);
                    if (!(old & bit)) {
                        int pos = atomicAdd(&scount[b], 1);
                        ast(&slist[b * NPT + pos], i);
                    }
                }
            }
        }
    }
    gridbar(bar, 1);

    // ======================= Phase 2: MLP (v4, proven) ======================
    {
        const int s0 = ald(&scount[0]), s1 = ald(&scount[1]);
        const int s2 = ald(&scount[2]), s3 = ald(&scount[3]);
        short* A1 = (short*)smem;                 // 64*72*2 = 9216
        short* A2 = (short*)(smem + 9216);        // 9216
        short* A3 = (short*)(smem + 18432);       // 64*136*2 = 17408
        float* sx = (float*)(smem + 35840);       // 3*64*4 = 768

        const int lane = t & 63;
        const int w    = __builtin_amdgcn_readfirstlane(t >> 6);  // 0..15
        const int m    = lane & 15, quad = lane >> 4;
        const int b    = blk & 3;                 // block-constant batch
        const int z    = (blk >> 2) & 3;          // block-constant oc5 slice
        const int cnt  = (b==0) ? s0 : (b==1) ? s1 : (b==2) ? s2 : s3;

        // hoisted weight fragments (block-constant)
        const int ocA = (w >> 2) * 16 + m;
        bf16x8 bw2[2], bw3[2], bw4[2][2], bw5[4];
#pragma unroll
        for (int ks = 0; ks < 2; ++ks) {
            bw2[ks] = cvt8(w2 + ocA*64 + ks*32 + quad*8);
            bw3[ks] = cvt8(w3 + ocA*64 + ks*32 + quad*8);
        }
        int oc4i[2];
#pragma unroll
        for (int r2 = 0; r2 < 2; ++r2) {
            oc4i[r2] = ((w >> 2) + 4*r2) * 16 + m;
#pragma unroll
            for (int ks = 0; ks < 2; ++ks)
                bw4[r2][ks] = cvt8(w4 + oc4i[r2]*64 + ks*32 + quad*8);
        }
        const int oc5 = z*256 + w*16 + m;
#pragma unroll
        for (int ks = 0; ks < 4; ++ks)
            bw5[ks] = cvt8(w5 + oc5*128 + ks*32 + quad*8);
        const float bias2 = b2[ocA], bias3 = b3[ocA];
        const float bias4_0 = b4[oc4i[0]], bias4_1 = b4[oc4i[1]];
        const float bias5 = b5[oc5];
        float w1v[4][3], b1v[4];
#pragma unroll
        for (int i = 0; i < 4; ++i) {
            int oc = w*4 + i;
            w1v[i][0] = w1[oc*3+0]; w1v[i][1] = w1[oc*3+1]; w1v[i][2] = w1[oc*3+2];
            b1v[i] = b1[oc];
        }
        const int pt0 = (w & 3) * 16;             // pt tile for L2/L3/L4

        for (int xblk = blk >> 4; xblk * 64 < cnt; xblk += 4) {
            const int base = xblk << 6;
            const int npts = min(64, cnt - base);
            __syncthreads();                       // prev tile fully consumed
            if (t < 64) {
                int idx = ald(&slist[b * NPT + base + min(t, npts - 1)]);  // pad = dup last
                const float* xp = x + ((size_t)b * NPT + idx) * 3;
                sx[t] = xp[0]; sx[64 + t] = xp[1]; sx[128 + t] = xp[2];
            }
            __syncthreads();
            {   // L1: 3->64, fp32 VALU, write bf16 [pt][72]
                float x0 = sx[lane], x1 = sx[64 + lane], x2 = sx[128 + lane];
#pragma unroll
                for (int i = 0; i < 4; ++i) {
                    float acc = fmaf(x2, w1v[i][2], fmaf(x1, w1v[i][1],
                                 fmaf(x0, w1v[i][0], b1v[i])));
                    A1[lane*72 + w*4 + i] = f2bf(fmaxf(acc, 0.0f));
                }
            }
            __syncthreads();
            {   // L2: A1 -> A2 (64->64)
                bf16x8 a0 = *(const bf16x8*)&A1[(pt0 + m)*72 + quad*8];
                bf16x8 a1 = *(const bf16x8*)&A1[(pt0 + m)*72 + 32 + quad*8];
                f32x4 d = {0.f, 0.f, 0.f, 0.f};
                d = MFMA16(a0, bw2[0], d);
                d = MFMA16(a1, bw2[1], d);
#pragma unroll
                for (int r = 0; r < 4; ++r)
                    A2[(pt0 + quad*4 + r)*72 + ocA] = f2bf(fmaxf(d[r] + bias2, 0.0f));
            }
            __syncthreads();
            {   // L3: A2 -> A1 (64->64)
                bf16x8 a0 = *(const bf16x8*)&A2[(pt0 + m)*72 + quad*8];
                bf16x8 a1 = *(const bf16x8*)&A2[(pt0 + m)*72 + 32 + quad*8];
                f32x4 d = {0.f, 0.f, 0.f, 0.f};
                d = MFMA16(a0, bw3[0], d);
                d = MFMA16(a1, bw3[1], d);
#pragma unroll
                for (int r = 0; r < 4; ++r)
                    A1[(pt0 + quad*4 + r)*72 + ocA] = f2bf(fmaxf(d[r] + bias3, 0.0f));
            }
            __syncthreads();
            {   // L4: A1 -> A3 (64->128), 2 oc-tiles per wave
                bf16x8 a0 = *(const bf16x8*)&A1[(pt0 + m)*72 + quad*8];
                bf16x8 a1 = *(const bf16x8*)&A1[(pt0 + m)*72 + 32 + quad*8];
#pragma unroll
                for (int r2 = 0; r2 < 2; ++r2) {
                    f32x4 d = {0.f, 0.f, 0.f, 0.f};
                    d = MFMA16(a0, bw4[r2][0], d);
                    d = MFMA16(a1, bw4[r2][1], d);
                    float bs = r2 ? bias4_1 : bias4_0;
#pragma unroll
                    for (int r = 0; r < 4; ++r)
                        A3[(pt0 + quad*4 + r)*136 + oc4i[r2]] = f2bf(fmaxf(d[r] + bs, 0.0f));
                }
            }
            __syncthreads();
            {   // L5 (128 -> this block's 256-oc slice) + max-pool
                float vm = 0.0f;                   // relu outputs >= 0
#pragma unroll
                for (int pt4 = 0; pt4 < 4; ++pt4) {
                    const int q0 = pt4 * 16;
                    f32x4 d = {0.f, 0.f, 0.f, 0.f};
#pragma unroll
                    for (int ks = 0; ks < 4; ++ks) {
                        bf16x8 a = *(const bf16x8*)&A3[(q0 + m)*136 + ks*32 + quad*8];
                        d = MFMA16(a, bw5[ks], d);
                    }
#pragma unroll
                    for (int r = 0; r < 4; ++r)
                        vm = fmaxf(vm, fmaxf(d[r] + bias5, 0.0f));
                }
                vm = fmaxf(vm, __shfl_xor(vm, 16, 64));
                vm = fmaxf(vm, __shfl_xor(vm, 32, 64));
                if (lane < 16)
                    atomicMax((int*)&pool[b*NCC + z*256 + w*16 + lane], __float_as_int(vm));
            }
        }
    }
    // ---- barrier 2, split: fw1 slice preloads inside the wait window ----
    gb_arrive(bar, 2);
    float fw1r[32];
    {
        const int bo = blk >> 2;
        const int lane = t & 63, w = t >> 6;
#pragma unroll
        for (int i = 0; i < 2; ++i) {
            int o = bo * 32 + w * 2 + i;
#pragma unroll
            for (int j = 0; j < 16; ++j)
                fw1r[i*16 + j] = fw1[o*1024 + lane + (j << 6)];
        }
    }
    gb_wait(bar, 2);

    // ======================= Phase 3: head1 (proven math) ===================
    {
        const int bo = blk >> 2, b = blk & 3;      // 64 items: all blocks
        const int lane = t & 63, w = t >> 6;
        float* g = (float*)smem;                   // 4 KB
        g[t] = ald(&pool[b*NCC + t]);
        __syncthreads();
#pragma unroll
        for (int i = 0; i < 2; ++i) {
            int o = bo * 32 + w * 2 + i;
            float acc = 0.0f;
#pragma unroll
            for (int j = 0; j < 16; ++j) {
                int k = lane + (j << 6);
                acc += g[k] * fw1r[i*16 + j];      // same values, same FP order
            }
#pragma unroll
            for (int m = 1; m < 64; m <<= 1) acc += __shfl_xor(acc, m, 64);
            if (lane == 0) ast(&h1g[b*512 + o], fmaxf(acc + fb1[o], 0.0f));
        }
    }
    // ---- barrier 3, split: fw2 slice preloads inside the wait window ----
    gb_arrive(bar, 3);
    float fw2r[16];
    if (blk < 32) {
        const int bo = blk >> 2;
        const int lane = t & 63, w = t >> 6;
#pragma unroll
        for (int i = 0; i < 2; ++i) {
            int o = bo * 32 + w * 2 + i;
#pragma unroll
            for (int j = 0; j < 8; ++j)
                fw2r[i*8 + j] = fw2[o*512 + lane + (j << 6)];
        }
    }
    gb_wait(bar, 3);

    // ======================= Phase 4: head2 (proven math) ===================
    if (blk < 32) {
        const int bo = blk >> 2, b = blk & 3;      // 32 items
        const int lane = t & 63, w = t >> 6;
        float* h1 = (float*)smem;                  // 2 KB
        if (t < 512) h1[t] = ald(&h1g[b*512 + t]);
        __syncthreads();
#pragma unroll
        for (int i = 0; i < 2; ++i) {
            int o = bo * 32 + w * 2 + i;
            float acc = 0.0f;
#pragma unroll
            for (int j = 0; j < 8; ++j) {
                int k = lane + (j << 6);
                acc += h1[k] * fw2r[i*8 + j];      // same values, same FP order
            }
#pragma unroll
            for (int m = 1; m < 64; m <<= 1) acc += __shfl_xor(acc, m, 64);
            if (lane == 0) ast(&h2g[b*256 + o], fmaxf(acc + fb2[o], 0.0f));
        }
    }
    gridbar(bar, 4);

    // ======================= Phase 5: head3 (proven) ========================
    if (blk < 4) {
        const int b = blk;
        const int lane = t & 63, w = t >> 6;
        float* h2 = (float*)smem;                  // 1 KB
        if (t < 256) h2[t] = ald(&h2g[b*256 + t]);
        __syncthreads();
        if (t < 256 && w < 3) {
            float acc = 0.0f;
#pragma unroll
            for (int j = 0; j < 4; ++j) {
                int k = lane + (j << 6);
                acc += h2[k] * fw3[w*256 + k];
            }
#pragma unroll
            for (int m = 1; m < 64; m <<= 1) acc += __shfl_xor(acc, m, 64);
            if (lane == 0) out[b*3 + w] = acc + fb3[w];
        }
    }
}

extern "C" void kernel_launch(void* const* d_in, const int* in_sizes, int n_in,
                              void* d_out, int out_size, void* d_ws, size_t ws_size,
                              hipStream_t stream)
{
    const float* x    = (const float*)d_in[0];
    const int*   far0 = (const int*)  d_in[1];
    const float *w1 = (const float*)d_in[2],  *b1 = (const float*)d_in[3];
    const float *w2 = (const float*)d_in[4],  *b2 = (const float*)d_in[5];
    const float *w3 = (const float*)d_in[6],  *b3 = (const float*)d_in[7];
    const float *w4 = (const float*)d_in[8],  *b4 = (const float*)d_in[9];
    const float *w5 = (const float*)d_in[10], *b5 = (const float*)d_in[11];
    const float *fw1 = (const float*)d_in[12], *fb1 = (const float*)d_in[13];
    const float *fw2 = (const float*)d_in[14], *fb2 = (const float*)d_in[15];
    const float *fw3 = (const float*)d_in[16], *fb3 = (const float*)d_in[17];

    char* ws = (char*)d_ws;
    int*      ccount = (int*)     (ws + OFF_CCOUNT);
    int*      scount = (int*)     (ws + OFF_SCOUNT);
    unsigned* sbits  = (unsigned*)(ws + OFF_SBITS);
    float*    pool   = (float*)   (ws + OFF_POOL);
    int*      clist  = (int*)     (ws + OFF_CLIST);
    float*    h1g    = (float*)   (ws + OFF_H1);
    float*    h2g    = (float*)   (ws + OFF_H2);
    int*      slist  = (int*)     (ws + OFF_SLIST);
    unsigned* bar    = (unsigned*)(ws + OFF_BAR);

    // Barrier counters must be zero (workspace is poisoned each iteration).
    (void)hipMemsetAsync(bar, 0, 8 * sizeof(unsigned), stream);
    mega_kernel<<<NBLK, 1024, 0, stream>>>(x, far0,
        w1,b1, w2,b2, w3,b3, w4,b4, w5,b5, fw1,fb1, fw2,fb2, fw3,fb3,
        clist, ccount, scount, sbits, slist, pool, h1g, h2g, (float*)d_out, bar);
}

// Round 11
// 158.550 us; speedup vs baseline: 1.2058x; 1.0345x over previous
//
#include <hip/hip_runtime.h>

// Problem constants (fixed by setup_inputs / reference)
#define BN  4       // batch
#define NPT 16384   // points per batch
#define NCC 1024    // FPS centroids (cap on unique orbit length)
#define KNN 32      // neighbors

// KNN select parameters
#define HBINS    2048   // 11-bit level-1 histogram
#define CCH      2      // centroids per chunk-block (keys fit in regs)
#define CAND_CAP 768    // boundary-bin candidate cap (overflow -> exact drill)

#define NBLK 64         // fused-kernel grid (all co-resident on 256 CUs)

// Workspace layout (bytes). ~310 KB + barrier counters.
#define OFF_CCOUNT 0                          // BN ints
#define OFF_SCOUNT 64                         // BN ints
#define OFF_SBITS  128                        // BN*(NPT/32) u32 = 8 KB
#define OFF_POOL   (128 + BN*(NPT/32)*4)      // BN*NCC floats = 16 KB
#define OFF_CLIST  (OFF_POOL + BN*NCC*4)      // BN*NCC ints = 16 KB
#define OFF_H1     (OFF_CLIST + BN*NCC*4)     // BN*512 floats = 8 KB
#define OFF_H2     (OFF_H1 + BN*512*4)        // BN*256 floats = 4 KB
#define OFF_SLIST  (OFF_H2 + BN*256*4)        // BN*NPT ints = 256 KB
#define OFF_BAR    (OFF_SLIST + BN*NPT*4)     // 8 u32 barrier counters

typedef short bf16x8 __attribute__((ext_vector_type(8)));
typedef float f32x4  __attribute__((ext_vector_type(4)));
typedef float f32x2  __attribute__((ext_vector_type(2)));

__device__ __forceinline__ short f2bf(float f) {   // RNE fp32 -> bf16
    unsigned u = __float_as_uint(f);
    return (short)((u + 0x7fffu + ((u >> 16) & 1u)) >> 16);
}
__device__ __forceinline__ bf16x8 cvt8(const float* __restrict__ p) {
    bf16x8 v;
#pragma unroll
    for (int j = 0; j < 8; ++j) v[j] = f2bf(p[j]);
    return v;
}

// ---------------------------------------------------------------------------
// Cross-block transport: every word that crosses a block boundary moves as a
// RELAXED AGENT-scope atomic (sc1 -> coherence point). Writers never leave
// dirty lines in a non-coherent XCD L2; readers never hit stale lines. This
// removes the need for any release/acquire fence.
// ---------------------------------------------------------------------------
template <typename T>
__device__ __forceinline__ void ast(T* p, T v) {
    __hip_atomic_store(p, v, __ATOMIC_RELAXED, __HIP_MEMORY_SCOPE_AGENT);
}
template <typename T>
__device__ __forceinline__ T ald(const T* p) {
    return __hip_atomic_load(const_cast<T*>(p), __ATOMIC_RELAXED, __HIP_MEMORY_SCOPE_AGENT);
}

// ---------------------------------------------------------------------------
// Grid barrier v3 (PROVEN BEST -- R5: mega 72us, dur 157.36):
//  - arrival: relaxed fetch_add (64 total per barrier)
//  - poll: relaxed atomic LOAD, s_sleep(8) throttled (~512cy between polls;
//    R6-R10 falsified every variant: faster polling, per-group counters,
//    producer-consumer flags, 8-line tree, wait-window preloads -- each
//    +9..+40us. Single line + lockstep + slow read-only poll is the optimum.)
//  - NO fences: all cross-block data is sc1 atomics (ast/ald); the
//    s_waitcnt vmcnt(0) before s_barrier drains them to the coherence point
//    before the leader's arrival add.
// ---------------------------------------------------------------------------
__device__ __forceinline__ void gridbar(unsigned* __restrict__ bar, int ph) {
    __syncthreads();                                   // drains vmcnt: sc1 ops committed
    if (threadIdx.x == 0) {
        __hip_atomic_fetch_add(&bar[ph], 1u, __ATOMIC_RELAXED, __HIP_MEMORY_SCOPE_AGENT);
        while (__hip_atomic_load(&bar[ph], __ATOMIC_RELAXED, __HIP_MEMORY_SCOPE_AGENT)
               < (unsigned)NBLK)
            __builtin_amdgcn_s_sleep(8);
    }
    __syncthreads();                                   // broadcast within block
}

__device__ __forceinline__ unsigned key_of(float px, float py, float pz, float xn,
                                           float cx, float cy, float cz, float cn)
{
    float dot = __fadd_rn(__fadd_rn(__fmul_rn(cx,px), __fmul_rn(cy,py)), __fmul_rn(cz,pz));
    float d2  = __fsub_rn(__fadd_rn(cn, xn), __fmul_rn(2.0f, dot));
    unsigned u = __float_as_uint(d2);
    return u ^ ((u >> 31) ? 0xFFFFFFFFu : 0x80000000u);
}

__device__ __forceinline__ void wave_scan_bins(const unsigned* __restrict__ H,
    int nbins, int rem, int lane, int* __restrict__ out_bin, int* __restrict__ out_below)
{
    int per = nbins >> 6;
    int base = lane * per;
    unsigned part = 0;
    for (int q = 0; q < per; ++q) part += H[base + q];
    unsigned inc = part;
#pragma unroll
    for (int m = 1; m < 64; m <<= 1) {
        unsigned u = __shfl_up(inc, m, 64);
        if (lane >= m) inc += u;
    }
    unsigned exc = inc - part;
    unsigned long long mk = __ballot(exc < (unsigned)rem && inc >= (unsigned)rem);
    int src = __ffsll((long long)mk) - 1;
    if (lane == src) {
        unsigned run = exc; int bb = base;
        for (int q = 0; q < per; ++q) {
            unsigned h = H[base + q];
            if (run + h >= (unsigned)rem) { bb = base + q; break; }
            run += h;
        }
        *out_bin = bb; *out_below = (int)run;
    }
}

#define MFMA16(a, bfr, c) __builtin_amdgcn_mfma_f32_16x16x32_bf16(a, bfr, c, 0, 0, 0)

// ---------------------------------------------------------------------------
// Fused pipeline: FPS(v6) -> KNN(v5) -> MLP(v4) -> head1 -> head2 -> head3.
// Math bodies verbatim; transport = sc1 atomics; barriers = fence-free v3.
// This is the R5-benched configuration (157.36us, mega 72us) -- the measured
// optimum of this orchestration design space after 5 falsified variants.
// ---------------------------------------------------------------------------
__global__ __launch_bounds__(1024) void mega_kernel(const float* __restrict__ x,
    const int* __restrict__ far_init,
    const float* __restrict__ w1, const float* __restrict__ b1,
    const float* __restrict__ w2, const float* __restrict__ b2,
    const float* __restrict__ w3, const float* __restrict__ b3,
    const float* __restrict__ w4, const float* __restrict__ b4,
    const float* __restrict__ w5, const float* __restrict__ b5,
    const float* __restrict__ fw1, const float* __restrict__ fb1,
    const float* __restrict__ fw2, const float* __restrict__ fb2,
    const float* __restrict__ fw3, const float* __restrict__ fb3,
    int* __restrict__ clist, int* __restrict__ ccount, int* __restrict__ scount,
    unsigned* __restrict__ sbits, int* __restrict__ slist, float* __restrict__ pool,
    float* __restrict__ h1g, float* __restrict__ h2g, float* __restrict__ out,
    unsigned* __restrict__ bar)
{
    const int blk = blockIdx.x, t = threadIdx.x;
    // LDS overlay: max(FPS 16.4K, KNN 22.6K, MLP 36.6K, heads 4K)
    __shared__ __align__(16) char smem[36864];

    // ======================= Phase 0: FPS (v6, proven) ======================
    {
#pragma clang fp contract(off)
        if (blk < 4) {
            const int b = blk;
            unsigned char* seen = (unsigned char*)smem;
            unsigned long long* slot = (unsigned long long*)(smem + 16384);

            // ---- workspace zeroing for this batch (sc1: visible to all) ----
            if (t < 512) ast(&sbits[b*(NPT/32) + t], 0u);  // 512 u32
            ast(&pool[b*NCC + t], 0.0f);                   // 1024 floats
            if (t == 0) { ast(&ccount[b], 0); ast(&scount[b], 0); }

            const float* xb = x + (size_t)b * NPT * 3;
            f32x2 px[8], py[8], pz[8];
#pragma unroll
            for (int r = 0; r < 8; ++r) {
                int ia = t + ((2*r) << 10), ib = ia + 1024;
                px[r] = f32x2{xb[ia*3+0], xb[ib*3+0]};
                py[r] = f32x2{xb[ia*3+1], xb[ib*3+1]};
                pz[r] = f32x2{xb[ia*3+2], xb[ib*3+2]};
            }
            ((uint4*)seen)[t] = make_uint4(0,0,0,0);      // 1024 * 16B = 16 KB
            if (t == 0) { slot[0] = 0ull; slot[1] = 0ull; slot[2] = 0ull; }
            int prev_bx = far_init[b];                    // uniform
            __syncthreads();
            int pbs = __builtin_amdgcn_readfirstlane(prev_bx);
            float cx = xb[pbs*3], cy = xb[pbs*3+1], cz = xb[pbs*3+2];

            int done = 0;
            for (int it = 0; it < NCC-1; ++it) {
                const int p = it % 3;
                const f32x2 cX = {cx, cx}, cY = {cy, cy}, cZ = {cz, cz};
                float best = -1.0f; int bi = 0;
#pragma unroll
                for (int r = 0; r < 8; ++r) {
                    f32x2 dx = px[r] - cX;
                    f32x2 dy = py[r] - cY;
                    f32x2 dz = pz[r] - cZ;
                    f32x2 m1 = dx * dx;
                    f32x2 m2 = dy * dy;
                    f32x2 m3 = dz * dz;
                    f32x2 s  = (m1 + m2) + m3;            // exact grouping of reference
                    int ia = t + ((2*r) << 10);
                    if (s.x > best) { best = s.x; bi = ia; }       // strict >: first max
                    if (s.y > best) { best = s.y; bi = ia + 1024; }
                }
#pragma unroll
                for (int m = 1; m < 64; m <<= 1) {
                    float od = __shfl_xor(best, m, 64);
                    int   oi = __shfl_xor(bi,   m, 64);
                    if (od > best || (od == best && oi < bi)) { best = od; bi = oi; }
                }
                if ((t & 63) == 0) {
                    unsigned long long pk =
                        (((unsigned long long)__float_as_uint(best)) << 32)
                        | (unsigned)(NPT - 1 - bi);
                    atomicMax(&slot[p], pk);
                }
                if (t == 0) seen[prev_bx] = 1;            // pre-barrier write
                __syncthreads();                          // THE barrier
                int bx = NPT - 1 - (int)(unsigned)(slot[p] & 0xFFFFFFFFull);
                if (t == 0) slot[(it + 2) % 3] = 0ull;    // barrier-separated both ways
                if (seen[bx]) { done = 1; break; }        // uniform
                prev_bx = bx;
                int bxs = __builtin_amdgcn_readfirstlane(bx);
                cx = xb[bxs*3]; cy = xb[bxs*3+1]; cz = xb[bxs*3+2];
            }
            if (!done && t == 0) seen[prev_bx] = 1;       // full orbit: mark last
            __syncthreads();
#pragma unroll
            for (int j = 0; j < 16; ++j) {
                int idx = t + (j << 10);
                if (seen[idx]) {
                    int pos = atomicAdd(&ccount[b], 1);
                    ast(&clist[b * NCC + pos], idx);
                }
            }
        }
    }
    gridbar(bar, 0);

    // ======================= Phase 1: KNN (v5, proven) ======================
    {
        const int c0 = ald(&ccount[0]), c1 = ald(&ccount[1]);
        const int c2 = ald(&ccount[2]), c3 = ald(&ccount[3]);
        const int maxc = max(max(c0,c1), max(c2,c3));
        unsigned* hist    = (unsigned*)smem;               // 16384 B
        unsigned* cand    = (unsigned*)(smem + 16384);     // 6144 B
        float*    cpx     = (float*)(smem + 22528);
        float*    cpy     = cpx + CCH;
        float*    cpz     = cpy + CCH;
        float*    cpn     = cpz + CCH;
        unsigned* candCnt = (unsigned*)(cpn + CCH);
        int*      s_bb    = (int*)(candCnt + CCH);
        int*      s_below = s_bb + CCH;
        int*      s_rrem  = s_below + CCH;
        int*      s_need  = s_rrem + CCH;
        int*      s_pref  = s_need + CCH;
        unsigned* s_tau   = (unsigned*)(s_pref + CCH);
        int*      s_tb    = (int*)(s_tau + CCH);           // [0]=tbin [1]=tbelow

        const int lane = t & 63, w = t >> 6;

        for (int wi = blk; (wi >> 2) * CCH < maxc; wi += NBLK) {
            const int b = wi & 3;
            const int cnt = (b==0) ? c0 : (b==1) ? c1 : (b==2) ? c2 : c3;
            const int cbase = (wi >> 2) * CCH;
            if (cbase >= cnt) continue;                    // block-uniform
            const float* xb = x + (size_t)b * NPT * 3;

            __syncthreads();                               // defensive item fence
            if (t < CCH) {
                int ci = ald(&clist[b * NCC + min(cbase + t, cnt - 1)]);  // tail-clamp dup
                float cx = xb[ci*3], cy = xb[ci*3+1], cz = xb[ci*3+2];
                cpx[t] = cx; cpy[t] = cy; cpz[t] = cz;
                cpn[t] = __fadd_rn(__fadd_rn(__fmul_rn(cx,cx), __fmul_rn(cy,cy)), __fmul_rn(cz,cz));
                candCnt[t] = 0;
            }
            for (int i = t; i < CCH * HBINS; i += 1024) hist[i] = 0;
            __syncthreads();

            // Sweep 1: compute keys ONCE into registers + build histograms.
            unsigned keys[NPT/1024][CCH];                  // 16 x 2 u32 = 32 VGPRs
#pragma unroll
            for (int j = 0; j < NPT/1024; ++j) {
                int i = t + (j << 10);
                float px = xb[i*3], py = xb[i*3+1], pz = xb[i*3+2];
                float xn = __fadd_rn(__fadd_rn(__fmul_rn(px,px), __fmul_rn(py,py)), __fmul_rn(pz,pz));
#pragma unroll
                for (int c = 0; c < CCH; ++c) {
                    unsigned key = key_of(px,py,pz,xn, cpx[c],cpy[c],cpz[c],cpn[c]);
                    keys[j][c] = key;
                    atomicAdd(&hist[c*HBINS + (key >> 21)], 1u);
                }
            }
            __syncthreads();

            if (w < CCH)
                wave_scan_bins(&hist[w*HBINS], HBINS, KNN, lane, &s_bb[w], &s_below[w]);
            __syncthreads();
            if (t < CCH) s_rrem[t] = KNN - s_below[t];
            __syncthreads();

            // Sweep 2 (registers only): collect candidate keys in boundary bins.
#pragma unroll
            for (int j = 0; j < NPT/1024; ++j) {
#pragma unroll
                for (int c = 0; c < CCH; ++c) {
                    unsigned key = keys[j][c];
                    if ((int)(key >> 21) == s_bb[c]) {
                        unsigned pos = atomicAdd(&candCnt[c], 1u);
                        if (pos < CAND_CAP) cand[c*CAND_CAP + pos] = key;
                    }
                }
            }
            __syncthreads();

            // Exact tau: rank-select per wave.
            if (w < CCH) {
                unsigned cc = candCnt[w];
                if (cc <= CAND_CAP) {
                    int r = s_rrem[w] - 1;
                    const unsigned* C = &cand[w*CAND_CAP];
                    for (int idx = lane; idx < (int)cc; idx += 64) {
                        unsigned k = C[idx]; int rank = 0;
                        for (int q = 0; q < (int)cc; ++q) {
                            unsigned kq = C[q];
                            rank += (kq < k || (kq == k && q < idx)) ? 1 : 0;
                        }
                        if (rank == r) s_tau[w] = k;
                    }
                    if (lane == 0) s_need[w] = 0;
                } else if (lane == 0) s_need[w] = 1;
            }
            __syncthreads();

            // Rare exact drill-down for overflowed boundary bins.
            for (int c = 0; c < CCH; ++c) {
                if (s_need[c]) {
                    const float cx = cpx[c], cy = cpy[c], cz = cpz[c], cn = cpn[c];
                    for (int i = t; i < HBINS; i += 1024) hist[i] = 0;
                    __syncthreads();
                    for (int j = 0; j < NPT/1024; ++j) {
                        int i = t + (j << 10);
                        float px = xb[i*3], py = xb[i*3+1], pz = xb[i*3+2];
                        float xn = __fadd_rn(__fadd_rn(__fmul_rn(px,px), __fmul_rn(py,py)), __fmul_rn(pz,pz));
                        unsigned key = key_of(px,py,pz,xn, cx,cy,cz,cn);
                        if ((int)(key >> 21) == s_bb[c]) atomicAdd(&hist[(key >> 10) & 2047u], 1u);
                    }
                    __syncthreads();
                    if (w == 0) wave_scan_bins(hist, HBINS, s_rrem[c], lane, &s_tb[0], &s_tb[1]);
                    __syncthreads();
                    if (t == 0) { s_pref[c] = (s_bb[c] << 11) | s_tb[0]; s_rrem[c] -= s_tb[1]; }
                    __syncthreads();
                    for (int i = t; i < 1024; i += 1024) hist[i] = 0;
                    __syncthreads();
                    for (int j = 0; j < NPT/1024; ++j) {
                        int i = t + (j << 10);
                        float px = xb[i*3], py = xb[i*3+1], pz = xb[i*3+2];
                        float xn = __fadd_rn(__fadd_rn(__fmul_rn(px,px), __fmul_rn(py,py)), __fmul_rn(pz,pz));
                        unsigned key = key_of(px,py,pz,xn, cx,cy,cz,cn);
                        if ((int)(key >> 10) == s_pref[c]) atomicAdd(&hist[key & 1023u], 1u);
                    }
                    __syncthreads();
                    if (w == 0) wave_scan_bins(hist, 1024, s_rrem[c], lane, &s_tb[0], &s_tb[1]);
                    __syncthreads();
                    if (t == 0) s_tau[c] = (((unsigned)s_pref[c]) << 10) | (unsigned)s_tb[0];
                    __syncthreads();
                }
            }
            __syncthreads();

            // Sweep 3 (registers only): union-mark + build compacted list (deduped).
#pragma unroll
            for (int j = 0; j < NPT/1024; ++j) {
                int i = t + (j << 10);
                bool sel = false;
#pragma unroll
                for (int c = 0; c < CCH; ++c) sel |= (keys[j][c] <= s_tau[c]);
                if (sel) {
                    unsigned bit = 1u << (i & 31);
                    unsigned old = atomicOr(&sbits[b*(NPT/32) + (i >> 5)], bit);
                    if (!(old & bit)) {
                        int pos = atomicAdd(&scount[b], 1);
                        ast(&slist[b * NPT + pos], i);
                    }
                }
            }
        }
    }
    gridbar(bar, 1);

    // ======================= Phase 2: MLP (v4, proven) ======================
    {
        const int s0 = ald(&scount[0]), s1 = ald(&scount[1]);
        const int s2 = ald(&scount[2]), s3 = ald(&scount[3]);
        short* A1 = (short*)smem;                 // 64*72*2 = 9216
        short* A2 = (short*)(smem + 9216);        // 9216
        short* A3 = (short*)(smem + 18432);       // 64*136*2 = 17408
        float* sx = (float*)(smem + 35840);       // 3*64*4 = 768

        const int lane = t & 63;
        const int w    = __builtin_amdgcn_readfirstlane(t >> 6);  // 0..15
        const int m    = lane & 15, quad = lane >> 4;
        const int b    = blk & 3;                 // block-constant batch
        const int z    = (blk >> 2) & 3;          // block-constant oc5 slice
        const int cnt  = (b==0) ? s0 : (b==1) ? s1 : (b==2) ? s2 : s3;

        // hoisted weight fragments (block-constant)
        const int ocA = (w >> 2) * 16 + m;
        bf16x8 bw2[2], bw3[2], bw4[2][2], bw5[4];
#pragma unroll
        for (int ks = 0; ks < 2; ++ks) {
            bw2[ks] = cvt8(w2 + ocA*64 + ks*32 + quad*8);
            bw3[ks] = cvt8(w3 + ocA*64 + ks*32 + quad*8);
        }
        int oc4i[2];
#pragma unroll
        for (int r2 = 0; r2 < 2; ++r2) {
            oc4i[r2] = ((w >> 2) + 4*r2) * 16 + m;
#pragma unroll
            for (int ks = 0; ks < 2; ++ks)
                bw4[r2][ks] = cvt8(w4 + oc4i[r2]*64 + ks*32 + quad*8);
        }
        const int oc5 = z*256 + w*16 + m;
#pragma unroll
        for (int ks = 0; ks < 4; ++ks)
            bw5[ks] = cvt8(w5 + oc5*128 + ks*32 + quad*8);
        const float bias2 = b2[ocA], bias3 = b3[ocA];
        const float bias4_0 = b4[oc4i[0]], bias4_1 = b4[oc4i[1]];
        const float bias5 = b5[oc5];
        float w1v[4][3], b1v[4];
#pragma unroll
        for (int i = 0; i < 4; ++i) {
            int oc = w*4 + i;
            w1v[i][0] = w1[oc*3+0]; w1v[i][1] = w1[oc*3+1]; w1v[i][2] = w1[oc*3+2];
            b1v[i] = b1[oc];
        }
        const int pt0 = (w & 3) * 16;             // pt tile for L2/L3/L4

        for (int xblk = blk >> 4; xblk * 64 < cnt; xblk += 4) {
            const int base = xblk << 6;
            const int npts = min(64, cnt - base);
            __syncthreads();                       // prev tile fully consumed
            if (t < 64) {
                int idx = ald(&slist[b * NPT + base + min(t, npts - 1)]);  // pad = dup last
                const float* xp = x + ((size_t)b * NPT + idx) * 3;
                sx[t] = xp[0]; sx[64 + t] = xp[1]; sx[128 + t] = xp[2];
            }
            __syncthreads();
            {   // L1: 3->64, fp32 VALU, write bf16 [pt][72]
                float x0 = sx[lane], x1 = sx[64 + lane], x2 = sx[128 + lane];
#pragma unroll
                for (int i = 0; i < 4; ++i) {
                    float acc = fmaf(x2, w1v[i][2], fmaf(x1, w1v[i][1],
                                 fmaf(x0, w1v[i][0], b1v[i])));
                    A1[lane*72 + w*4 + i] = f2bf(fmaxf(acc, 0.0f));
                }
            }
            __syncthreads();
            {   // L2: A1 -> A2 (64->64)
                bf16x8 a0 = *(const bf16x8*)&A1[(pt0 + m)*72 + quad*8];
                bf16x8 a1 = *(const bf16x8*)&A1[(pt0 + m)*72 + 32 + quad*8];
                f32x4 d = {0.f, 0.f, 0.f, 0.f};
                d = MFMA16(a0, bw2[0], d);
                d = MFMA16(a1, bw2[1], d);
#pragma unroll
                for (int r = 0; r < 4; ++r)
                    A2[(pt0 + quad*4 + r)*72 + ocA] = f2bf(fmaxf(d[r] + bias2, 0.0f));
            }
            __syncthreads();
            {   // L3: A2 -> A1 (64->64)
                bf16x8 a0 = *(const bf16x8*)&A2[(pt0 + m)*72 + quad*8];
                bf16x8 a1 = *(const bf16x8*)&A2[(pt0 + m)*72 + 32 + quad*8];
                f32x4 d = {0.f, 0.f, 0.f, 0.f};
                d = MFMA16(a0, bw3[0], d);
                d = MFMA16(a1, bw3[1], d);
#pragma unroll
                for (int r = 0; r < 4; ++r)
                    A1[(pt0 + quad*4 + r)*72 + ocA] = f2bf(fmaxf(d[r] + bias3, 0.0f));
            }
            __syncthreads();
            {   // L4: A1 -> A3 (64->128), 2 oc-tiles per wave
                bf16x8 a0 = *(const bf16x8*)&A1[(pt0 + m)*72 + quad*8];
                bf16x8 a1 = *(const bf16x8*)&A1[(pt0 + m)*72 + 32 + quad*8];
#pragma unroll
                for (int r2 = 0; r2 < 2; ++r2) {
                    f32x4 d = {0.f, 0.f, 0.f, 0.f};
                    d = MFMA16(a0, bw4[r2][0], d);
                    d = MFMA16(a1, bw4[r2][1], d);
                    float bs = r2 ? bias4_1 : bias4_0;
#pragma unroll
                    for (int r = 0; r < 4; ++r)
                        A3[(pt0 + quad*4 + r)*136 + oc4i[r2]] = f2bf(fmaxf(d[r] + bs, 0.0f));
                }
            }
            __syncthreads();
            {   // L5 (128 -> this block's 256-oc slice) + max-pool
                float vm = 0.0f;                   // relu outputs >= 0
#pragma unroll
                for (int pt4 = 0; pt4 < 4; ++pt4) {
                    const int q0 = pt4 * 16;
                    f32x4 d = {0.f, 0.f, 0.f, 0.f};
#pragma unroll
                    for (int ks = 0; ks < 4; ++ks) {
                        bf16x8 a = *(const bf16x8*)&A3[(q0 + m)*136 + ks*32 + quad*8];
                        d = MFMA16(a, bw5[ks], d);
                    }
#pragma unroll
                    for (int r = 0; r < 4; ++r)
                        vm = fmaxf(vm, fmaxf(d[r] + bias5, 0.0f));
                }
                vm = fmaxf(vm, __shfl_xor(vm, 16, 64));
                vm = fmaxf(vm, __shfl_xor(vm, 32, 64));
                if (lane < 16)
                    atomicMax((int*)&pool[b*NCC + z*256 + w*16 + lane], __float_as_int(vm));
            }
        }
    }
    gridbar(bar, 2);

    // ======================= Phase 3: head1 (proven) ========================
    {
        const int bo = blk >> 2, b = blk & 3;      // 64 items: all blocks
        const int lane = t & 63, w = t >> 6;
        float* g = (float*)smem;                   // 4 KB
        g[t] = ald(&pool[b*NCC + t]);
        __syncthreads();
#pragma unroll
        for (int i = 0; i < 2; ++i) {
            int o = bo * 32 + w * 2 + i;
            float acc = 0.0f;
#pragma unroll
            for (int j = 0; j < 16; ++j) {
                int k = lane + (j << 6);
                acc += g[k] * fw1[o*1024 + k];
            }
#pragma unroll
            for (int m = 1; m < 64; m <<= 1) acc += __shfl_xor(acc, m, 64);
            if (lane == 0) ast(&h1g[b*512 + o], fmaxf(acc + fb1[o], 0.0f));
        }
    }
    gridbar(bar, 3);

    // ======================= Phase 4: head2 (proven) ========================
    if (blk < 32) {
        const int bo = blk >> 2, b = blk & 3;      // 32 items
        const int lane = t & 63, w = t >> 6;
        float* h1 = (float*)smem;                  // 2 KB
        if (t < 512) h1[t] = ald(&h1g[b*512 + t]);
        __syncthreads();
#pragma unroll
        for (int i = 0; i < 2; ++i) {
            int o = bo * 32 + w * 2 + i;
            float acc = 0.0f;
#pragma unroll
            for (int j = 0; j < 8; ++j) {
                int k = lane + (j << 6);
                acc += h1[k] * fw2[o*512 + k];
            }
#pragma unroll
            for (int m = 1; m < 64; m <<= 1) acc += __shfl_xor(acc, m, 64);
            if (lane == 0) ast(&h2g[b*256 + o], fmaxf(acc + fb2[o], 0.0f));
        }
    }
    gridbar(bar, 4);

    // ======================= Phase 5: head3 (proven) ========================
    if (blk < 4) {
        const int b = blk;
        const int lane = t & 63, w = t >> 6;
        float* h2 = (float*)smem;                  // 1 KB
        if (t < 256) h2[t] = ald(&h2g[b*256 + t]);
        __syncthreads();
        if (t < 256 && w < 3) {
            float acc = 0.0f;
#pragma unroll
            for (int j = 0; j < 4; ++j) {
                int k = lane + (j << 6);
                acc += h2[k] * fw3[w*256 + k];
            }
#pragma unroll
            for (int m = 1; m < 64; m <<= 1) acc += __shfl_xor(acc, m, 64);
            if (lane == 0) out[b*3 + w] = acc + fb3[w];
        }
    }
}

extern "C" void kernel_launch(void* const* d_in, const int* in_sizes, int n_in,
                              void* d_out, int out_size, void* d_ws, size_t ws_size,
                              hipStream_t stream)
{
    const float* x    = (const float*)d_in[0];
    const int*   far0 = (const int*)  d_in[1];
    const float *w1 = (const float*)d_in[2],  *b1 = (const float*)d_in[3];
    const float *w2 = (const float*)d_in[4],  *b2 = (const float*)d_in[5];
    const float *w3 = (const float*)d_in[6],  *b3 = (const float*)d_in[7];
    const float *w4 = (const float*)d_in[8],  *b4 = (const float*)d_in[9];
    const float *w5 = (const float*)d_in[10], *b5 = (const float*)d_in[11];
    const float *fw1 = (const float*)d_in[12], *fb1 = (const float*)d_in[13];
    const float *fw2 = (const float*)d_in[14], *fb2 = (const float*)d_in[15];
    const float *fw3 = (const float*)d_in[16], *fb3 = (const float*)d_in[17];

    char* ws = (char*)d_ws;
    int*      ccount = (int*)     (ws + OFF_CCOUNT);
    int*      scount = (int*)     (ws + OFF_SCOUNT);
    unsigned* sbits  = (unsigned*)(ws + OFF_SBITS);
    float*    pool   = (float*)   (ws + OFF_POOL);
    int*      clist  = (int*)     (ws + OFF_CLIST);
    float*    h1g    = (float*)   (ws + OFF_H1);
    float*    h2g    = (float*)   (ws + OFF_H2);
    int*      slist  = (int*)     (ws + OFF_SLIST);
    unsigned* bar    = (unsigned*)(ws + OFF_BAR);

    // Barrier counters must be zero (workspace is poisoned each iteration).
    (void)hipMemsetAsync(bar, 0, 8 * sizeof(unsigned), stream);
    mega_kernel<<<NBLK, 1024, 0, stream>>>(x, far0,
        w1,b1, w2,b2, w3,b3, w4,b4, w5,b5, fw1,fb1, fw2,fb2, fw3,fb3,
        clist, ccount, scount, sbits, slist, pool, h1g, h2g, (float*)d_out, bar);
}